// Round 1
// baseline (424.671 us; speedup 1.0000x reference)
//
#include <hip/hip_runtime.h>
#include <hip/hip_bf16.h>
#include <cfloat>

#define NN 4096
#define DD 256
#define KTOP 10
#define MTOP 5
#define MUSEL 2048
#define NCLS 31

typedef unsigned long long u64;
typedef unsigned int u32;

// ---------------- kernel 1: row squared norms (src rows then tgt rows) -------
__global__ __launch_bounds__(256) void rowsq_kernel(const float* __restrict__ src,
                                                    const float* __restrict__ tgt,
                                                    float* __restrict__ sq_s,
                                                    float* __restrict__ sq_t) {
    int r = blockIdx.x; // 0..2N-1
    const float* base = (r < NN) ? (src + (size_t)r * DD) : (tgt + (size_t)(r - NN) * DD);
    float v = base[threadIdx.x];
    float p = v * v;
    for (int off = 32; off > 0; off >>= 1) p += __shfl_down(p, off);
    __shared__ float red[4];
    int wid = threadIdx.x >> 6, lane = threadIdx.x & 63;
    if (lane == 0) red[wid] = p;
    __syncthreads();
    if (threadIdx.x == 0) {
        float s = red[0] + red[1] + red[2] + red[3];
        if (r < NN) sq_s[r] = s; else sq_t[r - NN] = s;
    }
}

// ---------------- kernel 2: fp32 GEMM -> simT[j][i] --------------------------
#define TILE 64
#define BK 32
#define LDT 68   // padded leading dim (float4-aligned, breaks bank stride)

__global__ __launch_bounds__(256) void gemm_sim_kernel(const float* __restrict__ src,
                                                       const float* __restrict__ tgt,
                                                       const float* __restrict__ sq_s,
                                                       const float* __restrict__ sq_t,
                                                       float* __restrict__ simT) {
    __shared__ __attribute__((aligned(16))) float As[BK][LDT]; // tgt tile, As[k][jj]
    __shared__ __attribute__((aligned(16))) float Bs[BK][LDT]; // src tile, Bs[k][ii]
    int tid = threadIdx.x;
    int i0 = blockIdx.x * TILE;   // source dim
    int j0 = blockIdx.y * TILE;   // target dim
    int lrow = tid >> 3;          // 0..31
    int lk4  = (tid & 7) << 2;    // 0,4,..,28
    int tx = tid & 15;            // i-quad
    int ty = tid >> 4;            // j-quad
    float acc[4][4];
#pragma unroll
    for (int a = 0; a < 4; ++a)
#pragma unroll
        for (int b = 0; b < 4; ++b) acc[a][b] = 0.f;

    for (int k0 = 0; k0 < DD; k0 += BK) {
        __syncthreads();
#pragma unroll
        for (int r = 0; r < 2; ++r) {
            int row = lrow + r * 32;
            float4 va = *(const float4*)(tgt + (size_t)(j0 + row) * DD + k0 + lk4);
            As[lk4 + 0][row] = va.x; As[lk4 + 1][row] = va.y;
            As[lk4 + 2][row] = va.z; As[lk4 + 3][row] = va.w;
            float4 vb = *(const float4*)(src + (size_t)(i0 + row) * DD + k0 + lk4);
            Bs[lk4 + 0][row] = vb.x; Bs[lk4 + 1][row] = vb.y;
            Bs[lk4 + 2][row] = vb.z; Bs[lk4 + 3][row] = vb.w;
        }
        __syncthreads();
#pragma unroll
        for (int k = 0; k < BK; ++k) {
            float4 a4 = *(const float4*)&As[k][ty << 2];
            float4 b4 = *(const float4*)&Bs[k][tx << 2];
            float av[4] = {a4.x, a4.y, a4.z, a4.w};
            float bv[4] = {b4.x, b4.y, b4.z, b4.w};
#pragma unroll
            for (int jj = 0; jj < 4; ++jj)
#pragma unroll
                for (int ii = 0; ii < 4; ++ii)
                    acc[jj][ii] = fmaf(av[jj], bv[ii], acc[jj][ii]);
        }
    }
#pragma unroll
    for (int jj = 0; jj < 4; ++jj) {
        int j = j0 + (ty << 2) + jj;
        float sqt = sq_t[j];
        float tmp[4];
#pragma unroll
        for (int ii = 0; ii < 4; ++ii) {
            int i = i0 + (tx << 2) + ii;
            float d2 = sq_s[i] + sqt - 2.0f * acc[jj][ii];
            d2 = fmaxf(d2, 0.0f);
            tmp[ii] = 1.0f / (sqrtf(d2) + 1.0f);
        }
        float4 o; o.x = tmp[0]; o.y = tmp[1]; o.z = tmp[2]; o.w = tmp[3];
        *(float4*)(simT + (size_t)j * NN + i0 + (tx << 2)) = o;
    }
}

// ---------------- kernel 3: per-target top-k vote + score --------------------
// key = (float_bits(v) << 32) | (0xFFFFFFFF - idx): order == (v desc, idx asc),
// matching lax.top_k tie-break exactly (all v >= 0 so bit order == value order).
__global__ __launch_bounds__(256) void percol_kernel(const float* __restrict__ simT,
                                                     const int* __restrict__ labels,
                                                     int* __restrict__ assigned,
                                                     float* __restrict__ score) {
    __shared__ float vals[NN];
    __shared__ unsigned char labs[NN];
    __shared__ u64 red[4];
    __shared__ int cnts[32];
    __shared__ int s_asg;
    int tid = threadIdx.x;
    int j = blockIdx.x;
    for (int t = 0; t < 16; ++t) {
        int idx = t * 256 + tid;
        vals[idx] = simT[(size_t)j * NN + idx];
        labs[idx] = (unsigned char)labels[idx];
    }
    if (tid < 32) cnts[tid] = 0;
    __syncthreads();

    // ---- top-10 + label votes ----
    u64 prev = ~0ull;
    for (int k = 0; k < KTOP; ++k) {
        u64 best = 0;
        for (int t = 0; t < 16; ++t) {
            int idx = t * 256 + tid;
            u64 key = ((u64)__float_as_uint(vals[idx]) << 32) | (u64)(0xFFFFFFFFu - (u32)idx);
            if (key < prev && key > best) best = key;
        }
        for (int off = 32; off > 0; off >>= 1) {
            u64 o = __shfl_down(best, off);
            if (o > best) best = o;
        }
        if ((tid & 63) == 0) red[tid >> 6] = best;
        __syncthreads();
        u64 m01 = red[0] > red[1] ? red[0] : red[1];
        u64 m23 = red[2] > red[3] ? red[2] : red[3];
        prev = m01 > m23 ? m01 : m23;
        if (tid == 0) {
            int idx = (int)(0xFFFFFFFFu - (u32)prev);
            cnts[labs[idx]] += 1;
        }
        __syncthreads();
    }
    if (tid == 0) {
        int bestc = -1, basg = 0;
        for (int c = 0; c < NCLS; ++c)
            if (cnts[c] > bestc) { bestc = cnts[c]; basg = c; } // first-max == jnp.argmax
        s_asg = basg;
    }
    __syncthreads();
    int asg = s_asg;

    // ---- top-5 same-label sum (masked values = 0, matching where(same,sim,0)) ----
    float nln = 0.f;
    prev = ~0ull;
    for (int k = 0; k < MTOP; ++k) {
        u64 best = 0;
        for (int t = 0; t < 16; ++t) {
            int idx = t * 256 + tid;
            float v = ((int)labs[idx] == asg) ? vals[idx] : 0.0f;
            u64 key = ((u64)__float_as_uint(v) << 32) | (u64)(0xFFFFFFFFu - (u32)idx);
            if (key < prev && key > best) best = key;
        }
        for (int off = 32; off > 0; off >>= 1) {
            u64 o = __shfl_down(best, off);
            if (o > best) best = o;
        }
        if ((tid & 63) == 0) red[tid >> 6] = best;
        __syncthreads();
        u64 m01 = red[0] > red[1] ? red[0] : red[1];
        u64 m23 = red[2] > red[3] ? red[2] : red[3];
        prev = m01 > m23 ? m01 : m23;
        nln += __uint_as_float((u32)(prev >> 32));
        __syncthreads();
    }
    // ---- top-5 diff-label sum ----
    float nun = 0.f;
    prev = ~0ull;
    for (int k = 0; k < MTOP; ++k) {
        u64 best = 0;
        for (int t = 0; t < 16; ++t) {
            int idx = t * 256 + tid;
            float v = ((int)labs[idx] != asg) ? vals[idx] : 0.0f;
            u64 key = ((u64)__float_as_uint(v) << 32) | (u64)(0xFFFFFFFFu - (u32)idx);
            if (key < prev && key > best) best = key;
        }
        for (int off = 32; off > 0; off >>= 1) {
            u64 o = __shfl_down(best, off);
            if (o > best) best = o;
        }
        if ((tid & 63) == 0) red[tid >> 6] = best;
        __syncthreads();
        u64 m01 = red[0] > red[1] ? red[0] : red[1];
        u64 m23 = red[2] > red[3] ? red[2] : red[3];
        prev = m01 > m23 ? m01 : m23;
        nun += __uint_as_float((u32)(prev >> 32));
        __syncthreads();
    }
    if (tid == 0) {
        assigned[j] = asg;
        score[j] = nln / nun;
    }
}

// ---------------- kernel 4: single-block bitonic sort, take top MU -----------
__global__ __launch_bounds__(1024) void sort_kernel(const float* __restrict__ score,
                                                    int* __restrict__ top_tgt) {
    __shared__ u64 keys[NN];
    int tid = threadIdx.x;
    for (int i = tid; i < NN; i += 1024)
        keys[i] = ((u64)__float_as_uint(score[i]) << 32) | (u64)(0xFFFFFFFFu - (u32)i);
    __syncthreads();
    for (int k = 2; k <= NN; k <<= 1) {
        for (int s = k >> 1; s > 0; s >>= 1) {
            for (int i = tid; i < NN; i += 1024) {
                int l = i ^ s;
                if (l > i) {
                    u64 a = keys[i], b = keys[l];
                    bool sw = ((i & k) == 0) ? (a < b) : (a > b); // descending sort
                    if (sw) { keys[i] = b; keys[l] = a; }
                }
            }
            __syncthreads();
        }
    }
    for (int i = tid; i < MUSEL; i += 1024)
        top_tgt[i] = (int)(0xFFFFFFFFu - (u32)keys[i]);
}

// ---------------- kernel 5: flab + class histogram ---------------------------
__global__ __launch_bounds__(1024) void flab_kernel(const int* __restrict__ top_tgt,
                                                    const int* __restrict__ assigned,
                                                    int* __restrict__ flab,
                                                    int* __restrict__ hist) {
    __shared__ int h[32];
    int tid = threadIdx.x;
    if (tid < 32) h[tid] = 0;
    __syncthreads();
    for (int r = tid; r < MUSEL; r += 1024) {
        int a = assigned[top_tgt[r]];
        flab[r] = a;
        atomicAdd(&h[a], 1);
    }
    __syncthreads();
    if (tid < 32) hist[tid] = h[tid];
}

// ---------------- kernel 6: online-softmax partials --------------------------
#define JCH 128
__global__ __launch_bounds__(256) void fpart_kernel(const float* __restrict__ simT,
                                                    const int* __restrict__ top_tgt,
                                                    const int* __restrict__ flab,
                                                    const int* __restrict__ labels,
                                                    float* __restrict__ pm,
                                                    float* __restrict__ ps,
                                                    float* __restrict__ pt) {
    __shared__ int tt[JCH];
    __shared__ int fl[JCH];
    int tid = threadIdx.x;
    int ci = blockIdx.x, cj = blockIdx.y;
    if (tid < JCH) { tt[tid] = top_tgt[cj * JCH + tid]; fl[tid] = flab[cj * JCH + tid]; }
    __syncthreads();
    int i = ci * 256 + tid;
    int myl = labels[i];
    float m = -FLT_MAX, s = 0.f, t = 0.f;
    for (int jj = 0; jj < JCH; ++jj) {
        float v = simT[(size_t)tt[jj] * NN + i];
        float msk = (fl[jj] == myl) ? 1.0f : 0.0f;
        if (v > m) {
            float e = expf(m - v);
            s = s * e + 1.0f;
            t = t * e + msk;
            m = v;
        } else {
            float e = expf(v - m);
            s += e;
            t += msk * e;
        }
    }
    pm[cj * NN + i] = m;
    ps[cj * NN + i] = s;
    pt[cj * NN + i] = t;
}

// ---------------- kernel 7: merge partials -> per-block loss partials --------
__global__ __launch_bounds__(256) void merge_kernel(const float* __restrict__ pm,
                                                    const float* __restrict__ ps,
                                                    const float* __restrict__ pt,
                                                    const int* __restrict__ labels,
                                                    const int* __restrict__ hist,
                                                    float* __restrict__ partials) {
    int tid = threadIdx.x;
    int i = blockIdx.x * 256 + tid;
    float M = -FLT_MAX, S = 0.f, T = 0.f;
    for (int c = 0; c < 16; ++c) {
        float mc = pm[c * NN + i], sc = ps[c * NN + i], tc = pt[c * NN + i];
        float nM = fmaxf(M, mc);
        float e1 = expf(M - nM), e2 = expf(mc - nM);
        S = S * e1 + sc * e2;
        T = T * e1 + tc * e2;
        M = nM;
    }
    float contr = T / S;
    int ns = hist[labels[i]];
    bool valid = (ns > 0) && (ns < MUSEL);
    float term = valid ? logf(contr) : 0.0f;
    float cnt = valid ? 1.0f : 0.0f;
    for (int off = 32; off > 0; off >>= 1) {
        term += __shfl_down(term, off);
        cnt  += __shfl_down(cnt, off);
    }
    __shared__ float rt[4], rc[4];
    int wid = tid >> 6, lane = tid & 63;
    if (lane == 0) { rt[wid] = term; rc[wid] = cnt; }
    __syncthreads();
    if (tid == 0) {
        partials[blockIdx.x * 2]     = rt[0] + rt[1] + rt[2] + rt[3];
        partials[blockIdx.x * 2 + 1] = rc[0] + rc[1] + rc[2] + rc[3];
    }
}

// ---------------- kernel 8: final scalar -------------------------------------
__global__ void final_kernel(const float* __restrict__ partials, float* __restrict__ out) {
    if (threadIdx.x == 0) {
        float s = 0.f, c = 0.f;
        for (int b = 0; b < 16; ++b) { s += partials[b * 2]; c += partials[b * 2 + 1]; }
        out[0] = -s / c;
    }
}

extern "C" void kernel_launch(void* const* d_in, const int* in_sizes, int n_in,
                              void* d_out, int out_size, void* d_ws, size_t ws_size,
                              hipStream_t stream) {
    const float* src    = (const float*)d_in[0];
    const int*   labels = (const int*)d_in[1];
    const float* tgt    = (const float*)d_in[2];
    float* out = (float*)d_out;

    char* ws = (char*)d_ws;
    size_t off = 0;
    float* simT = (float*)(ws + off);      off += (size_t)NN * NN * sizeof(float); // 64 MB
    float* sq_s = (float*)(ws + off);      off += NN * sizeof(float);
    float* sq_t = (float*)(ws + off);      off += NN * sizeof(float);
    float* score = (float*)(ws + off);     off += NN * sizeof(float);
    int*   assigned = (int*)(ws + off);    off += NN * sizeof(int);
    int*   top_tgt = (int*)(ws + off);     off += MUSEL * sizeof(int);
    int*   flab = (int*)(ws + off);        off += MUSEL * sizeof(int);
    int*   hist = (int*)(ws + off);        off += 32 * sizeof(int);
    float* pm = (float*)(ws + off);        off += 16 * NN * sizeof(float);
    float* ps = (float*)(ws + off);        off += 16 * NN * sizeof(float);
    float* pt = (float*)(ws + off);        off += 16 * NN * sizeof(float);
    float* partials = (float*)(ws + off);  off += 32 * sizeof(float);

    rowsq_kernel<<<2 * NN, 256, 0, stream>>>(src, tgt, sq_s, sq_t);
    gemm_sim_kernel<<<dim3(NN / TILE, NN / TILE), 256, 0, stream>>>(src, tgt, sq_s, sq_t, simT);
    percol_kernel<<<NN, 256, 0, stream>>>(simT, labels, assigned, score);
    sort_kernel<<<1, 1024, 0, stream>>>(score, top_tgt);
    flab_kernel<<<1, 1024, 0, stream>>>(top_tgt, assigned, flab, hist);
    fpart_kernel<<<dim3(16, 16), 256, 0, stream>>>(simT, top_tgt, flab, labels, pm, ps, pt);
    merge_kernel<<<16, 256, 0, stream>>>(pm, ps, pt, labels, hist, partials);
    final_kernel<<<1, 64, 0, stream>>>(partials, out);
}

// Round 2
// 318.753 us; speedup vs baseline: 1.3323x; 1.3323x over previous
//
#include <hip/hip_runtime.h>
#include <hip/hip_bf16.h>
#include <cfloat>

#define NN 4096
#define DD 256
#define KTOP 10
#define MTOP 5
#define MUSEL 2048
#define NCLS 31

typedef unsigned long long u64;
typedef unsigned int u32;
typedef __attribute__((ext_vector_type(8))) short short8;   // 8 bf16 (4 VGPRs)
typedef __attribute__((ext_vector_type(4))) float f32x4;    // MFMA acc

static __device__ __forceinline__ unsigned short f2bf(float x) {
    u32 u = __float_as_uint(x);
    u32 r = (u + 0x7FFFu + ((u >> 16) & 1u)) >> 16;   // RNE, no NaN inputs here
    return (unsigned short)r;
}
static __device__ __forceinline__ float bf2f(unsigned short h) {
    return __uint_as_float((u32)h << 16);
}

// ---------------- kernel 0: fp32 -> bf16 hi/lo planes ------------------------
__global__ __launch_bounds__(256) void conv_kernel(const float* __restrict__ src,
                                                   const float* __restrict__ tgt,
                                                   unsigned short* __restrict__ src_hi,
                                                   unsigned short* __restrict__ src_lo,
                                                   unsigned short* __restrict__ tgt_hi,
                                                   unsigned short* __restrict__ tgt_lo) {
    size_t idx = (size_t)blockIdx.x * 256 + threadIdx.x;
    float x = src[idx];
    unsigned short h = f2bf(x);
    src_hi[idx] = h;
    src_lo[idx] = f2bf(x - bf2f(h));
    float y = tgt[idx];
    unsigned short g = f2bf(y);
    tgt_hi[idx] = g;
    tgt_lo[idx] = f2bf(y - bf2f(g));
}

// ---------------- kernel 1: row squared norms --------------------------------
__global__ __launch_bounds__(256) void rowsq_kernel(const float* __restrict__ src,
                                                    const float* __restrict__ tgt,
                                                    float* __restrict__ sq_s,
                                                    float* __restrict__ sq_t) {
    int r = blockIdx.x; // 0..2N-1
    const float* base = (r < NN) ? (src + (size_t)r * DD) : (tgt + (size_t)(r - NN) * DD);
    float v = base[threadIdx.x];
    float p = v * v;
    for (int off = 32; off > 0; off >>= 1) p += __shfl_down(p, off);
    __shared__ float red[4];
    int wid = threadIdx.x >> 6, lane = threadIdx.x & 63;
    if (lane == 0) red[wid] = p;
    __syncthreads();
    if (threadIdx.x == 0) {
        float s = red[0] + red[1] + red[2] + red[3];
        if (r < NN) sq_s[r] = s; else sq_t[r - NN] = s;
    }
}

// ---------------- kernel 2: bf16 MFMA GEMM (hi/lo 3-term) -> simT ------------
// simT[j][i] = 1/(sqrt(max(||s_i||^2+||t_j||^2-2*dot,0))+1)
// dot = hi_t.hi_s (seg0) + hi_t.lo_s (seg1) + lo_t.hi_s (seg2)
__global__ __launch_bounds__(256) void gemm_mfma_kernel(
        const unsigned short* __restrict__ tgt_hi, const unsigned short* __restrict__ tgt_lo,
        const unsigned short* __restrict__ src_hi, const unsigned short* __restrict__ src_lo,
        const float* __restrict__ sq_s, const float* __restrict__ sq_t,
        float* __restrict__ simT) {
    __shared__ short Atile[128 * 32];  // [row j'][k] 64B/row
    __shared__ short Btile[128 * 32];  // [row i'][k]
    int tid = threadIdx.x;
    int wid = tid >> 6, lane = tid & 63;
    int i0 = blockIdx.x * 128;   // source dim (N of GEMM)
    int j0 = blockIdx.y * 128;   // target dim (M of GEMM)
    int wr = wid >> 1, wc = wid & 1;

    f32x4 acc[4][4];
#pragma unroll
    for (int m = 0; m < 4; ++m)
#pragma unroll
        for (int n = 0; n < 4; ++n) acc[m][n] = (f32x4){0.f, 0.f, 0.f, 0.f};

    // staging geometry: chunk c (=wid*2+r) covers tile rows [c*16, c*16+16),
    // lane writes bytes lane*16 of the 1024B chunk -> row c*16+lane/4, k-off (lane&3)*8
    int srow = wid * 32 + (lane >> 2);
    int skoff = (lane & 3) * 8;
    int fr = lane & 15;            // fragment row/col within 16
    int kq = (lane >> 4) * 8;      // fragment k offset

    for (int t = 0; t < 24; ++t) {
        int seg = t >> 3;
        int kk = (t & 7) * 32;
        const unsigned short* Abase = (seg < 2) ? tgt_hi : tgt_lo;
        const unsigned short* Bbase = (seg == 1) ? src_lo : src_hi;
#pragma unroll
        for (int r = 0; r < 2; ++r) {
            int row = srow + r * 16;
            const unsigned short* ga = Abase + (size_t)(j0 + row) * DD + kk + skoff;
            short* la = Atile + (wid * 2 + r) * 512;   // wave-uniform base
            __builtin_amdgcn_global_load_lds((const __attribute__((address_space(1))) void*)ga,
                                             (__attribute__((address_space(3))) void*)la, 16, 0, 0);
            const unsigned short* gb = Bbase + (size_t)(i0 + row) * DD + kk + skoff;
            short* lb = Btile + (wid * 2 + r) * 512;
            __builtin_amdgcn_global_load_lds((const __attribute__((address_space(1))) void*)gb,
                                             (__attribute__((address_space(3))) void*)lb, 16, 0, 0);
        }
        __syncthreads();
        short8 af[4], bfv[4];
#pragma unroll
        for (int m = 0; m < 4; ++m) {
            af[m]  = *(const short8*)(Atile + (wr * 64 + m * 16 + fr) * 32 + kq);
            bfv[m] = *(const short8*)(Btile + (wc * 64 + m * 16 + fr) * 32 + kq);
        }
#pragma unroll
        for (int m = 0; m < 4; ++m)
#pragma unroll
            for (int n = 0; n < 4; ++n)
                acc[m][n] = __builtin_amdgcn_mfma_f32_16x16x32_bf16(af[m], bfv[n], acc[m][n], 0, 0, 0);
        __syncthreads();
    }

    // epilogue: C/D layout col=lane&15 (i), row=(lane>>4)*4+reg (j)
    int fq = lane >> 4;
#pragma unroll
    for (int m = 0; m < 4; ++m) {
#pragma unroll
        for (int n = 0; n < 4; ++n) {
            int i = i0 + wc * 64 + n * 16 + fr;
            float ss = sq_s[i];
#pragma unroll
            for (int r = 0; r < 4; ++r) {
                int j = j0 + wr * 64 + m * 16 + fq * 4 + r;
                float d2 = fmaxf(ss + sq_t[j] - 2.0f * acc[m][n][r], 0.0f);
                simT[(size_t)j * NN + i] = 1.0f / (sqrtf(d2) + 1.0f);
            }
        }
    }
}

// ---------------- kernel 3: per-target top-k vote + score --------------------
// key = (float_bits(v) << 32) | (0xFFFFFFFF - idx): order == (v desc, idx asc)
__global__ __launch_bounds__(256) void percol_kernel(const float* __restrict__ simT,
                                                     const int* __restrict__ labels,
                                                     int* __restrict__ assigned,
                                                     float* __restrict__ score) {
    __shared__ unsigned char labs[NN];
    __shared__ u64 red[2][4];
    __shared__ int cnts[32];
    __shared__ int s_asg;
    int tid = threadIdx.x;
    int j = blockIdx.x;
    float v[16];
    int lab[16];
#pragma unroll
    for (int t = 0; t < 16; ++t) {
        int idx = t * 256 + tid;
        v[t] = simT[(size_t)j * NN + idx];
        int l = labels[idx];
        lab[t] = l;
        labs[idx] = (unsigned char)l;
    }
    if (tid < 32) cnts[tid] = 0;
    __syncthreads();

    // ---- top-10 + label votes ----
    u64 prev = ~0ull;
    for (int k = 0; k < KTOP; ++k) {
        u64 best = 0;
#pragma unroll
        for (int t = 0; t < 16; ++t) {
            u64 key = ((u64)__float_as_uint(v[t]) << 32) | (u64)(0xFFFFFFFFu - (u32)(t * 256 + tid));
            if (key < prev && key > best) best = key;
        }
        for (int off = 32; off > 0; off >>= 1) {
            u64 o = __shfl_down(best, off);
            if (o > best) best = o;
        }
        if ((tid & 63) == 0) red[k & 1][tid >> 6] = best;
        __syncthreads();
        u64 m01 = red[k & 1][0] > red[k & 1][1] ? red[k & 1][0] : red[k & 1][1];
        u64 m23 = red[k & 1][2] > red[k & 1][3] ? red[k & 1][2] : red[k & 1][3];
        prev = m01 > m23 ? m01 : m23;
        if (tid == 0) cnts[labs[0xFFFFFFFFu - (u32)prev]] += 1;
    }
    if (tid == 0) {
        int bestc = -1, basg = 0;
        for (int c = 0; c < NCLS; ++c)
            if (cnts[c] > bestc) { bestc = cnts[c]; basg = c; } // first-max == argmax
        s_asg = basg;
    }
    __syncthreads();
    int asg = s_asg;

    // ---- top-5 same-label sum ----
    float nln = 0.f;
    prev = ~0ull;
    for (int k = 0; k < MTOP; ++k) {
        u64 best = 0;
#pragma unroll
        for (int t = 0; t < 16; ++t) {
            float mv = (lab[t] == asg) ? v[t] : 0.0f;
            u64 key = ((u64)__float_as_uint(mv) << 32) | (u64)(0xFFFFFFFFu - (u32)(t * 256 + tid));
            if (key < prev && key > best) best = key;
        }
        for (int off = 32; off > 0; off >>= 1) {
            u64 o = __shfl_down(best, off);
            if (o > best) best = o;
        }
        if ((tid & 63) == 0) red[k & 1][tid >> 6] = best;
        __syncthreads();
        u64 m01 = red[k & 1][0] > red[k & 1][1] ? red[k & 1][0] : red[k & 1][1];
        u64 m23 = red[k & 1][2] > red[k & 1][3] ? red[k & 1][2] : red[k & 1][3];
        prev = m01 > m23 ? m01 : m23;
        nln += __uint_as_float((u32)(prev >> 32));
    }
    // ---- top-5 diff-label sum ----
    float nun = 0.f;
    prev = ~0ull;
    for (int k = 0; k < MTOP; ++k) {
        u64 best = 0;
#pragma unroll
        for (int t = 0; t < 16; ++t) {
            float mv = (lab[t] != asg) ? v[t] : 0.0f;
            u64 key = ((u64)__float_as_uint(mv) << 32) | (u64)(0xFFFFFFFFu - (u32)(t * 256 + tid));
            if (key < prev && key > best) best = key;
        }
        for (int off = 32; off > 0; off >>= 1) {
            u64 o = __shfl_down(best, off);
            if (o > best) best = o;
        }
        if ((tid & 63) == 0) red[k & 1][tid >> 6] = best;
        __syncthreads();
        u64 m01 = red[k & 1][0] > red[k & 1][1] ? red[k & 1][0] : red[k & 1][1];
        u64 m23 = red[k & 1][2] > red[k & 1][3] ? red[k & 1][2] : red[k & 1][3];
        prev = m01 > m23 ? m01 : m23;
        nun += __uint_as_float((u32)(prev >> 32));
    }
    if (tid == 0) {
        assigned[j] = asg;
        score[j] = nln / nun;
    }
}

// ---------------- kernel 4: single-block bitonic sort, take top MU -----------
__global__ __launch_bounds__(1024) void sort_kernel(const float* __restrict__ score,
                                                    int* __restrict__ top_tgt) {
    __shared__ u64 keys[NN];
    int tid = threadIdx.x;
    for (int i = tid; i < NN; i += 1024)
        keys[i] = ((u64)__float_as_uint(score[i]) << 32) | (u64)(0xFFFFFFFFu - (u32)i);
    __syncthreads();
    for (int k = 2; k <= NN; k <<= 1) {
        for (int s = k >> 1; s > 0; s >>= 1) {
            for (int i = tid; i < NN; i += 1024) {
                int l = i ^ s;
                if (l > i) {
                    u64 a = keys[i], b = keys[l];
                    bool sw = ((i & k) == 0) ? (a < b) : (a > b); // descending
                    if (sw) { keys[i] = b; keys[l] = a; }
                }
            }
            __syncthreads();
        }
    }
    for (int i = tid; i < MUSEL; i += 1024)
        top_tgt[i] = (int)(0xFFFFFFFFu - (u32)keys[i]);
}

// ---------------- kernel 5: flab + class histogram ---------------------------
__global__ __launch_bounds__(1024) void flab_kernel(const int* __restrict__ top_tgt,
                                                    const int* __restrict__ assigned,
                                                    int* __restrict__ flab,
                                                    int* __restrict__ hist) {
    __shared__ int h[32];
    int tid = threadIdx.x;
    if (tid < 32) h[tid] = 0;
    __syncthreads();
    for (int r = tid; r < MUSEL; r += 1024) {
        int a = assigned[top_tgt[r]];
        flab[r] = a;
        atomicAdd(&h[a], 1);
    }
    __syncthreads();
    if (tid < 32) hist[tid] = h[tid];
}

// ---------------- kernel 6: online-softmax partials --------------------------
#define JCH 128
__global__ __launch_bounds__(256) void fpart_kernel(const float* __restrict__ simT,
                                                    const int* __restrict__ top_tgt,
                                                    const int* __restrict__ flab,
                                                    const int* __restrict__ labels,
                                                    float* __restrict__ pm,
                                                    float* __restrict__ ps,
                                                    float* __restrict__ pt) {
    __shared__ int tt[JCH];
    __shared__ int fl[JCH];
    int tid = threadIdx.x;
    int ci = blockIdx.x, cj = blockIdx.y;
    if (tid < JCH) { tt[tid] = top_tgt[cj * JCH + tid]; fl[tid] = flab[cj * JCH + tid]; }
    __syncthreads();
    int i = ci * 256 + tid;
    int myl = labels[i];
    float m = -FLT_MAX, s = 0.f, t = 0.f;
    for (int jj = 0; jj < JCH; ++jj) {
        float v = simT[(size_t)tt[jj] * NN + i];
        float msk = (fl[jj] == myl) ? 1.0f : 0.0f;
        if (v > m) {
            float e = expf(m - v);
            s = s * e + 1.0f;
            t = t * e + msk;
            m = v;
        } else {
            float e = expf(v - m);
            s += e;
            t += msk * e;
        }
    }
    pm[cj * NN + i] = m;
    ps[cj * NN + i] = s;
    pt[cj * NN + i] = t;
}

// ---------------- kernel 7: merge partials -> per-block loss partials --------
__global__ __launch_bounds__(256) void merge_kernel(const float* __restrict__ pm,
                                                    const float* __restrict__ ps,
                                                    const float* __restrict__ pt,
                                                    const int* __restrict__ labels,
                                                    const int* __restrict__ hist,
                                                    float* __restrict__ partials) {
    int tid = threadIdx.x;
    int i = blockIdx.x * 256 + tid;
    float M = -FLT_MAX, S = 0.f, T = 0.f;
    for (int c = 0; c < 16; ++c) {
        float mc = pm[c * NN + i], sc = ps[c * NN + i], tc = pt[c * NN + i];
        float nM = fmaxf(M, mc);
        float e1 = expf(M - nM), e2 = expf(mc - nM);
        S = S * e1 + sc * e2;
        T = T * e1 + tc * e2;
        M = nM;
    }
    float contr = T / S;
    int ns = hist[labels[i]];
    bool valid = (ns > 0) && (ns < MUSEL);
    float term = valid ? logf(contr) : 0.0f;
    float cnt = valid ? 1.0f : 0.0f;
    for (int off = 32; off > 0; off >>= 1) {
        term += __shfl_down(term, off);
        cnt  += __shfl_down(cnt, off);
    }
    __shared__ float rt[4], rc[4];
    int wid = tid >> 6, lane = tid & 63;
    if (lane == 0) { rt[wid] = term; rc[wid] = cnt; }
    __syncthreads();
    if (tid == 0) {
        partials[blockIdx.x * 2]     = rt[0] + rt[1] + rt[2] + rt[3];
        partials[blockIdx.x * 2 + 1] = rc[0] + rc[1] + rc[2] + rc[3];
    }
}

// ---------------- kernel 8: final scalar -------------------------------------
__global__ void final_kernel(const float* __restrict__ partials, float* __restrict__ out) {
    if (threadIdx.x == 0) {
        float s = 0.f, c = 0.f;
        for (int b = 0; b < 16; ++b) { s += partials[b * 2]; c += partials[b * 2 + 1]; }
        out[0] = -s / c;
    }
}

extern "C" void kernel_launch(void* const* d_in, const int* in_sizes, int n_in,
                              void* d_out, int out_size, void* d_ws, size_t ws_size,
                              hipStream_t stream) {
    const float* src    = (const float*)d_in[0];
    const int*   labels = (const int*)d_in[1];
    const float* tgt    = (const float*)d_in[2];
    float* out = (float*)d_out;

    char* ws = (char*)d_ws;
    size_t off = 0;
    float* simT = (float*)(ws + off);             off += (size_t)NN * NN * sizeof(float); // 64 MB
    unsigned short* tgt_hi = (unsigned short*)(ws + off); off += (size_t)NN * DD * 2;     // 2 MB
    unsigned short* tgt_lo = (unsigned short*)(ws + off); off += (size_t)NN * DD * 2;
    unsigned short* src_hi = (unsigned short*)(ws + off); off += (size_t)NN * DD * 2;
    unsigned short* src_lo = (unsigned short*)(ws + off); off += (size_t)NN * DD * 2;
    float* sq_s = (float*)(ws + off);      off += NN * sizeof(float);
    float* sq_t = (float*)(ws + off);      off += NN * sizeof(float);
    float* score = (float*)(ws + off);     off += NN * sizeof(float);
    int*   assigned = (int*)(ws + off);    off += NN * sizeof(int);
    int*   top_tgt = (int*)(ws + off);     off += MUSEL * sizeof(int);
    int*   flab = (int*)(ws + off);        off += MUSEL * sizeof(int);
    int*   hist = (int*)(ws + off);        off += 32 * sizeof(int);
    float* partials = (float*)(ws + off);  off += 32 * sizeof(float);
    // pm/ps/pt (256 KB each) alias the dead-after-GEMM bf16 planes
    float* pm = (float*)tgt_hi;
    float* ps = (float*)tgt_lo;
    float* pt = (float*)src_hi;

    conv_kernel<<<(NN * DD) / 256, 256, 0, stream>>>(src, tgt, src_hi, src_lo, tgt_hi, tgt_lo);
    rowsq_kernel<<<2 * NN, 256, 0, stream>>>(src, tgt, sq_s, sq_t);
    gemm_mfma_kernel<<<dim3(NN / 128, NN / 128), 256, 0, stream>>>(tgt_hi, tgt_lo, src_hi, src_lo,
                                                                   sq_s, sq_t, simT);
    percol_kernel<<<NN, 256, 0, stream>>>(simT, labels, assigned, score);
    sort_kernel<<<1, 1024, 0, stream>>>(score, top_tgt);
    flab_kernel<<<1, 1024, 0, stream>>>(top_tgt, assigned, flab, hist);
    fpart_kernel<<<dim3(16, 16), 256, 0, stream>>>(simT, top_tgt, flab, labels, pm, ps, pt);
    merge_kernel<<<16, 256, 0, stream>>>(pm, ps, pt, labels, hist, partials);
    final_kernel<<<1, 64, 0, stream>>>(partials, out);
}

// Round 3
// 297.042 us; speedup vs baseline: 1.4297x; 1.0731x over previous
//
#include <hip/hip_runtime.h>
#include <hip/hip_bf16.h>
#include <cfloat>

#define NN 4096
#define DD 256
#define KTOP 10
#define MTOP 5
#define MUSEL 2048
#define NCLS 31

typedef unsigned long long u64;
typedef unsigned int u32;
typedef __attribute__((ext_vector_type(8))) short short8;   // 8 bf16 (4 VGPRs)
typedef __attribute__((ext_vector_type(4))) float f32x4;    // MFMA acc

static __device__ __forceinline__ unsigned short f2bf(float x) {
    u32 u = __float_as_uint(x);
    u32 r = (u + 0x7FFFu + ((u >> 16) & 1u)) >> 16;   // RNE, no NaN inputs here
    return (unsigned short)r;
}
static __device__ __forceinline__ float bf2f(unsigned short h) {
    return __uint_as_float((u32)h << 16);
}

static __device__ __forceinline__ u64 wave_max64(u64 x) {
#pragma unroll
    for (int off = 1; off < 64; off <<= 1) {
        u64 o = __shfl_xor((unsigned long long)x, off);
        if (o > x) x = o;
    }
    return x;
}

// ---------------- kernel 0: fp32 -> bf16 hi/lo planes ------------------------
__global__ __launch_bounds__(256) void conv_kernel(const float* __restrict__ src,
                                                   const float* __restrict__ tgt,
                                                   unsigned short* __restrict__ src_hi,
                                                   unsigned short* __restrict__ src_lo,
                                                   unsigned short* __restrict__ tgt_hi,
                                                   unsigned short* __restrict__ tgt_lo) {
    size_t idx = (size_t)blockIdx.x * 256 + threadIdx.x;
    float x = src[idx];
    unsigned short h = f2bf(x);
    src_hi[idx] = h;
    src_lo[idx] = f2bf(x - bf2f(h));
    float y = tgt[idx];
    unsigned short g = f2bf(y);
    tgt_hi[idx] = g;
    tgt_lo[idx] = f2bf(y - bf2f(g));
}

// ---------------- kernel 1: row squared norms --------------------------------
__global__ __launch_bounds__(256) void rowsq_kernel(const float* __restrict__ src,
                                                    const float* __restrict__ tgt,
                                                    float* __restrict__ sq_s,
                                                    float* __restrict__ sq_t) {
    int r = blockIdx.x; // 0..2N-1
    const float* base = (r < NN) ? (src + (size_t)r * DD) : (tgt + (size_t)(r - NN) * DD);
    float v = base[threadIdx.x];
    float p = v * v;
    for (int off = 32; off > 0; off >>= 1) p += __shfl_down(p, off);
    __shared__ float red[4];
    int wid = threadIdx.x >> 6, lane = threadIdx.x & 63;
    if (lane == 0) red[wid] = p;
    __syncthreads();
    if (threadIdx.x == 0) {
        float s = red[0] + red[1] + red[2] + red[3];
        if (r < NN) sq_s[r] = s; else sq_t[r - NN] = s;
    }
}

// ---------------- kernel 2: bf16 MFMA GEMM (hi/lo 3-term), 2-phase dbuf ------
static __device__ __forceinline__ void stage_tile(const unsigned short* __restrict__ Ab,
                                                  const unsigned short* __restrict__ Bb,
                                                  short* Ad, short* Bd,
                                                  int j0, int i0, int kk,
                                                  int srow, int skoff, int wid) {
#pragma unroll
    for (int r = 0; r < 2; ++r) {
        int row = srow + r * 16;
        const unsigned short* ga = Ab + (size_t)(j0 + row) * DD + kk + skoff;
        __builtin_amdgcn_global_load_lds((const __attribute__((address_space(1))) void*)ga,
                                         (__attribute__((address_space(3))) void*)(Ad + (wid * 2 + r) * 512),
                                         16, 0, 0);
        const unsigned short* gb = Bb + (size_t)(i0 + row) * DD + kk + skoff;
        __builtin_amdgcn_global_load_lds((const __attribute__((address_space(1))) void*)gb,
                                         (__attribute__((address_space(3))) void*)(Bd + (wid * 2 + r) * 512),
                                         16, 0, 0);
    }
}

__global__ __launch_bounds__(256) void gemm_mfma_kernel(
        const unsigned short* __restrict__ tgt_hi, const unsigned short* __restrict__ tgt_lo,
        const unsigned short* __restrict__ src_hi, const unsigned short* __restrict__ src_lo,
        const float* __restrict__ sq_s, const float* __restrict__ sq_t,
        float* __restrict__ simT) {
    __shared__ short Atile[2][128 * 32];  // [row j'][k] 64B/row, double-buffered
    __shared__ short Btile[2][128 * 32];  // [row i'][k]
    int tid = threadIdx.x;
    int wid = tid >> 6, lane = tid & 63;
    int i0 = blockIdx.x * 128;   // source dim
    int j0 = blockIdx.y * 128;   // target dim
    int wr = wid >> 1, wc = wid & 1;

    f32x4 acc[4][4];
#pragma unroll
    for (int m = 0; m < 4; ++m)
#pragma unroll
        for (int n = 0; n < 4; ++n) acc[m][n] = (f32x4){0.f, 0.f, 0.f, 0.f};

    int srow = wid * 32 + (lane >> 2);
    int skoff = (lane & 3) * 8;
    int fr = lane & 15;            // fragment row/col within 16
    int kq = (lane >> 4) * 8;      // fragment k offset

    // t -> (seg, kk): seg selects hi/lo operand pair, kk the 32-wide K slice
    stage_tile(tgt_hi, src_hi, Atile[0], Btile[0], j0, i0, 0, srow, skoff, wid);
    __syncthreads();
    int buf = 0;
    for (int t = 0; t < 24; ++t) {
        if (t < 23) {
            int tn = t + 1;
            int seg = tn >> 3;
            int kk = (tn & 7) * 32;
            const unsigned short* Ab = (seg < 2) ? tgt_hi : tgt_lo;
            const unsigned short* Bb = (seg == 1) ? src_lo : src_hi;
            stage_tile(Ab, Bb, Atile[buf ^ 1], Btile[buf ^ 1], j0, i0, kk, srow, skoff, wid);
        }
        short8 af[4], bfv[4];
#pragma unroll
        for (int m = 0; m < 4; ++m) {
            af[m]  = *(const short8*)(Atile[buf] + (wr * 64 + m * 16 + fr) * 32 + kq);
            bfv[m] = *(const short8*)(Btile[buf] + (wc * 64 + m * 16 + fr) * 32 + kq);
        }
#pragma unroll
        for (int m = 0; m < 4; ++m)
#pragma unroll
            for (int n = 0; n < 4; ++n)
                acc[m][n] = __builtin_amdgcn_mfma_f32_16x16x32_bf16(af[m], bfv[n], acc[m][n], 0, 0, 0);
        __syncthreads();   // drains vmcnt (staged data ready) + protects buf reuse
        buf ^= 1;
    }

    // epilogue: C/D layout col=lane&15 (i), row=(lane>>4)*4+reg (j)
    int fq = lane >> 4;
#pragma unroll
    for (int m = 0; m < 4; ++m) {
#pragma unroll
        for (int n = 0; n < 4; ++n) {
            int i = i0 + wc * 64 + n * 16 + fr;
            float ss = sq_s[i];
#pragma unroll
            for (int r = 0; r < 4; ++r) {
                int j = j0 + wr * 64 + m * 16 + fq * 4 + r;
                float d2 = fmaxf(ss + sq_t[j] - 2.0f * acc[m][n][r], 0.0f);
                simT[(size_t)j * NN + i] = 1.0f / (sqrtf(d2) + 1.0f);
            }
        }
    }
}

// ---------------- kernel 3: per-target top-k vote + score --------------------
// key = bits(v)<<32 | (0xFFFF-idx)<<8 | label : orders (v desc, idx asc), label free.
// 4 waves each own 1024 elems; wave-local top-k (no barriers) then redundant merge.
__global__ __launch_bounds__(256) void percol_kernel(const float* __restrict__ simT,
                                                     const int* __restrict__ labels,
                                                     int* __restrict__ assigned,
                                                     float* __restrict__ score) {
    __shared__ u64 f1[4 * KTOP];
    __shared__ u64 f2[4 * MTOP];
    int tid = threadIdx.x, wid = tid >> 6, lane = tid & 63;
    int j = blockIdx.x;
    u64 key[16];
#pragma unroll
    for (int r = 0; r < 16; ++r) {
        int idx = r * 256 + tid;           // wave w owns idx%256 in [w*64,w*64+64)
        float v = simT[(size_t)j * NN + idx];
        int l = labels[idx];
        key[r] = ((u64)__float_as_uint(v) << 32) | ((u64)(u32)(0xFFFFu - (u32)idx) << 8) | (u32)l;
    }

    // ---- phase 1: wave-local top-10 ----
    u64 prev = ~0ull;
    for (int k = 0; k < KTOP; ++k) {
        u64 best = 0;
#pragma unroll
        for (int r = 0; r < 16; ++r) { u64 kk = key[r]; if (kk < prev && kk > best) best = kk; }
        best = wave_max64(best);
        if (lane == 0) f1[wid * KTOP + k] = best;
        prev = best;
    }
    __syncthreads();
    // redundant merge of 40 finalists; lane<31 owns class `lane` for votes
    u64 mk = (lane < 4 * KTOP) ? f1[lane] : 0;
    int votes = 0;
    for (int k = 0; k < KTOP; ++k) {
        u64 b = wave_max64(mk);
        if (mk == b) mk = 0;
        if ((int)(b & 0xFFu) == lane) votes++;
    }
    u32 vk = (lane < NCLS) ? (((u32)votes << 6) | (63u - (u32)lane)) : 0u;
#pragma unroll
    for (int off = 1; off < 64; off <<= 1) { u32 o = __shfl_xor(vk, off); if (o > vk) vk = o; }
    int asg = 63 - (int)(vk & 63u);        // first-max tie-break == jnp.argmax

    // ---- phase 2: top-5 same-label ----
    u64 mk2[16];
#pragma unroll
    for (int r = 0; r < 16; ++r)
        mk2[r] = ((int)(key[r] & 0xFFu) == asg) ? key[r] : (key[r] & 0xFFFFFFFFull);
    prev = ~0ull;
    for (int k = 0; k < MTOP; ++k) {
        u64 best = 0;
#pragma unroll
        for (int r = 0; r < 16; ++r) { u64 kk = mk2[r]; if (kk < prev && kk > best) best = kk; }
        best = wave_max64(best);
        if (lane == 0) f2[wid * MTOP + k] = best;
        prev = best;
    }
    __syncthreads();
    float nln = 0.f;
    {
        u64 m2 = (lane < 4 * MTOP) ? f2[lane] : 0;
        for (int k = 0; k < MTOP; ++k) {
            u64 b = wave_max64(m2);
            if (m2 == b) m2 = 0;
            nln += __uint_as_float((u32)(b >> 32));   // descending order, matches ref sum
        }
    }
    __syncthreads();   // all waves done reading f2 before reuse

    // ---- phase 3: top-5 diff-label ----
#pragma unroll
    for (int r = 0; r < 16; ++r)
        mk2[r] = ((int)(key[r] & 0xFFu) != asg) ? key[r] : (key[r] & 0xFFFFFFFFull);
    prev = ~0ull;
    for (int k = 0; k < MTOP; ++k) {
        u64 best = 0;
#pragma unroll
        for (int r = 0; r < 16; ++r) { u64 kk = mk2[r]; if (kk < prev && kk > best) best = kk; }
        best = wave_max64(best);
        if (lane == 0) f2[wid * MTOP + k] = best;
        prev = best;
    }
    __syncthreads();
    float nun = 0.f;
    {
        u64 m2 = (lane < 4 * MTOP) ? f2[lane] : 0;
        for (int k = 0; k < MTOP; ++k) {
            u64 b = wave_max64(m2);
            if (m2 == b) m2 = 0;
            nun += __uint_as_float((u32)(b >> 32));
        }
    }
    if (tid == 0) {
        assigned[j] = asg;
        score[j] = nln / nun;
    }
}

// ---------------- kernel 4: single-block bitonic sort, take top MU -----------
__global__ __launch_bounds__(1024) void sort_kernel(const float* __restrict__ score,
                                                    int* __restrict__ top_tgt) {
    __shared__ u64 keys[NN];
    int tid = threadIdx.x;
    for (int i = tid; i < NN; i += 1024)
        keys[i] = ((u64)__float_as_uint(score[i]) << 32) | (u64)(0xFFFFFFFFu - (u32)i);
    __syncthreads();
    for (int k = 2; k <= NN; k <<= 1) {
        for (int s = k >> 1; s > 0; s >>= 1) {
            for (int i = tid; i < NN; i += 1024) {
                int l = i ^ s;
                if (l > i) {
                    u64 a = keys[i], b = keys[l];
                    bool sw = ((i & k) == 0) ? (a < b) : (a > b); // descending
                    if (sw) { keys[i] = b; keys[l] = a; }
                }
            }
            __syncthreads();
        }
    }
    for (int i = tid; i < MUSEL; i += 1024)
        top_tgt[i] = (int)(0xFFFFFFFFu - (u32)keys[i]);
}

// ---------------- kernel 5: flab + class histogram ---------------------------
__global__ __launch_bounds__(1024) void flab_kernel(const int* __restrict__ top_tgt,
                                                    const int* __restrict__ assigned,
                                                    int* __restrict__ flab,
                                                    int* __restrict__ hist) {
    __shared__ int h[32];
    int tid = threadIdx.x;
    if (tid < 32) h[tid] = 0;
    __syncthreads();
    for (int r = tid; r < MUSEL; r += 1024) {
        int a = assigned[top_tgt[r]];
        flab[r] = a;
        atomicAdd(&h[a], 1);
    }
    __syncthreads();
    if (tid < 32) hist[tid] = h[tid];
}

// ---------------- kernel 6: softmax partial sums (no max shift needed) -------
// sim in (0,1] so exp(v) <= e: direct sums are exact-equivalent to max-shifted.
#define JCH 128
__global__ __launch_bounds__(256) void fpart_kernel(const float* __restrict__ simT,
                                                    const int* __restrict__ top_tgt,
                                                    const int* __restrict__ flab,
                                                    const int* __restrict__ labels,
                                                    float* __restrict__ ps,
                                                    float* __restrict__ pt) {
    __shared__ int tt[JCH];
    __shared__ int fl[JCH];
    int tid = threadIdx.x;
    int ci = blockIdx.x, cj = blockIdx.y;
    if (tid < JCH) { tt[tid] = top_tgt[cj * JCH + tid]; fl[tid] = flab[cj * JCH + tid]; }
    __syncthreads();
    int i = ci * 256 + tid;
    int myl = labels[i];
    float s = 0.f, t = 0.f;
#pragma unroll 4
    for (int jj = 0; jj < JCH; ++jj) {
        float v = simT[(size_t)tt[jj] * NN + i];
        float e = __expf(v);
        s += e;
        t += (fl[jj] == myl) ? e : 0.f;
    }
    ps[cj * NN + i] = s;
    pt[cj * NN + i] = t;
}

// ---------------- kernel 7: merge partials -> per-block loss partials --------
__global__ __launch_bounds__(256) void merge_kernel(const float* __restrict__ ps,
                                                    const float* __restrict__ pt,
                                                    const int* __restrict__ labels,
                                                    const int* __restrict__ hist,
                                                    float* __restrict__ partials) {
    int tid = threadIdx.x;
    int i = blockIdx.x * 256 + tid;
    float S = 0.f, T = 0.f;
#pragma unroll
    for (int c = 0; c < 16; ++c) {
        S += ps[c * NN + i];
        T += pt[c * NN + i];
    }
    float contr = T / S;
    int ns = hist[labels[i]];
    bool valid = (ns > 0) && (ns < MUSEL);
    float term = valid ? __logf(contr) : 0.0f;
    float cnt = valid ? 1.0f : 0.0f;
    for (int off = 32; off > 0; off >>= 1) {
        term += __shfl_down(term, off);
        cnt  += __shfl_down(cnt, off);
    }
    __shared__ float rt[4], rc[4];
    int wid = tid >> 6, lane = tid & 63;
    if (lane == 0) { rt[wid] = term; rc[wid] = cnt; }
    __syncthreads();
    if (tid == 0) {
        partials[blockIdx.x * 2]     = rt[0] + rt[1] + rt[2] + rt[3];
        partials[blockIdx.x * 2 + 1] = rc[0] + rc[1] + rc[2] + rc[3];
    }
}

// ---------------- kernel 8: final scalar -------------------------------------
__global__ void final_kernel(const float* __restrict__ partials, float* __restrict__ out) {
    if (threadIdx.x == 0) {
        float s = 0.f, c = 0.f;
        for (int b = 0; b < 16; ++b) { s += partials[b * 2]; c += partials[b * 2 + 1]; }
        out[0] = -s / c;
    }
}

extern "C" void kernel_launch(void* const* d_in, const int* in_sizes, int n_in,
                              void* d_out, int out_size, void* d_ws, size_t ws_size,
                              hipStream_t stream) {
    const float* src    = (const float*)d_in[0];
    const int*   labels = (const int*)d_in[1];
    const float* tgt    = (const float*)d_in[2];
    float* out = (float*)d_out;

    char* ws = (char*)d_ws;
    size_t off = 0;
    float* simT = (float*)(ws + off);             off += (size_t)NN * NN * sizeof(float); // 64 MB
    unsigned short* tgt_hi = (unsigned short*)(ws + off); off += (size_t)NN * DD * 2;     // 2 MB
    unsigned short* tgt_lo = (unsigned short*)(ws + off); off += (size_t)NN * DD * 2;
    unsigned short* src_hi = (unsigned short*)(ws + off); off += (size_t)NN * DD * 2;
    unsigned short* src_lo = (unsigned short*)(ws + off); off += (size_t)NN * DD * 2;
    float* sq_s = (float*)(ws + off);      off += NN * sizeof(float);
    float* sq_t = (float*)(ws + off);      off += NN * sizeof(float);
    float* score = (float*)(ws + off);     off += NN * sizeof(float);
    int*   assigned = (int*)(ws + off);    off += NN * sizeof(int);
    int*   top_tgt = (int*)(ws + off);     off += MUSEL * sizeof(int);
    int*   flab = (int*)(ws + off);        off += MUSEL * sizeof(int);
    int*   hist = (int*)(ws + off);        off += 32 * sizeof(int);
    float* partials = (float*)(ws + off);  off += 32 * sizeof(float);
    // ps/pt (256 KB each) alias the dead-after-GEMM bf16 planes
    float* ps = (float*)tgt_lo;
    float* pt = (float*)src_hi;

    conv_kernel<<<(NN * DD) / 256, 256, 0, stream>>>(src, tgt, src_hi, src_lo, tgt_hi, tgt_lo);
    rowsq_kernel<<<2 * NN, 256, 0, stream>>>(src, tgt, sq_s, sq_t);
    gemm_mfma_kernel<<<dim3(NN / 128, NN / 128), 256, 0, stream>>>(tgt_hi, tgt_lo, src_hi, src_lo,
                                                                   sq_s, sq_t, simT);
    percol_kernel<<<NN, 256, 0, stream>>>(simT, labels, assigned, score);
    sort_kernel<<<1, 1024, 0, stream>>>(score, top_tgt);
    flab_kernel<<<1, 1024, 0, stream>>>(top_tgt, assigned, flab, hist);
    fpart_kernel<<<dim3(16, 16), 256, 0, stream>>>(simT, top_tgt, flab, labels, ps, pt);
    merge_kernel<<<16, 256, 0, stream>>>(ps, pt, labels, hist, partials);
    final_kernel<<<1, 64, 0, stream>>>(partials, out);
}

// Round 4
// 266.157 us; speedup vs baseline: 1.5956x; 1.1160x over previous
//
#include <hip/hip_runtime.h>
#include <hip/hip_bf16.h>
#include <cfloat>

#define NN 4096
#define DD 256
#define KTOP 10
#define MTOP 5
#define MUSEL 2048
#define NCLS 31

typedef unsigned long long u64;
typedef unsigned int u32;
typedef __attribute__((ext_vector_type(8))) short short8;   // 8 bf16 (4 VGPRs)
typedef __attribute__((ext_vector_type(4))) float f32x4;    // MFMA acc

static __device__ __forceinline__ unsigned short f2bf(float x) {
    u32 u = __float_as_uint(x);
    u32 r = (u + 0x7FFFu + ((u >> 16) & 1u)) >> 16;   // RNE, no NaN inputs here
    return (unsigned short)r;
}
static __device__ __forceinline__ float bf2f(unsigned short h) {
    return __uint_as_float((u32)h << 16);
}

// ---- DPP wave reductions: VALU pipe, zero DS ops ----------------------------
template <int CTRL>
static __device__ __forceinline__ u32 dppmov(u32 x) {
    return (u32)__builtin_amdgcn_update_dpp(0, (int)x, CTRL, 0xF, 0xF, true);
}
// max over 64 lanes of a u64 key; returns wave-uniform result (via readlane 63)
static __device__ __forceinline__ u64 wave_max64(u64 x) {
    u32 lo = (u32)x, hi = (u32)(x >> 32);
#define STEP64(C) { u32 nh = dppmov<C>(hi), nl = dppmov<C>(lo); \
                    bool g = (nh > hi) || (nh == hi && nl > lo); \
                    hi = g ? nh : hi; lo = g ? nl : lo; }
    STEP64(0x111) STEP64(0x112) STEP64(0x114) STEP64(0x118) STEP64(0x142) STEP64(0x143)
#undef STEP64
    u32 rh = (u32)__builtin_amdgcn_readlane((int)hi, 63);
    u32 rl = (u32)__builtin_amdgcn_readlane((int)lo, 63);
    return ((u64)rh << 32) | rl;
}
static __device__ __forceinline__ u32 wave_max32(u32 x) {
#define STEP32(C) { u32 n = dppmov<C>(x); x = (n > x) ? n : x; }
    STEP32(0x111) STEP32(0x112) STEP32(0x114) STEP32(0x118) STEP32(0x142) STEP32(0x143)
#undef STEP32
    return (u32)__builtin_amdgcn_readlane((int)x, 63);
}

// ---------------- kernel 0: fp32 -> bf16 hi/lo planes ------------------------
__global__ __launch_bounds__(256) void conv_kernel(const float* __restrict__ src,
                                                   const float* __restrict__ tgt,
                                                   unsigned short* __restrict__ src_hi,
                                                   unsigned short* __restrict__ src_lo,
                                                   unsigned short* __restrict__ tgt_hi,
                                                   unsigned short* __restrict__ tgt_lo) {
    size_t idx = (size_t)blockIdx.x * 256 + threadIdx.x;
    float x = src[idx];
    unsigned short h = f2bf(x);
    src_hi[idx] = h;
    src_lo[idx] = f2bf(x - bf2f(h));
    float y = tgt[idx];
    unsigned short g = f2bf(y);
    tgt_hi[idx] = g;
    tgt_lo[idx] = f2bf(y - bf2f(g));
}

// ---------------- kernel 1: row squared norms --------------------------------
__global__ __launch_bounds__(256) void rowsq_kernel(const float* __restrict__ src,
                                                    const float* __restrict__ tgt,
                                                    float* __restrict__ sq_s,
                                                    float* __restrict__ sq_t) {
    int r = blockIdx.x; // 0..2N-1
    const float* base = (r < NN) ? (src + (size_t)r * DD) : (tgt + (size_t)(r - NN) * DD);
    float v = base[threadIdx.x];
    float p = v * v;
    for (int off = 32; off > 0; off >>= 1) p += __shfl_down(p, off);
    __shared__ float red[4];
    int wid = threadIdx.x >> 6, lane = threadIdx.x & 63;
    if (lane == 0) red[wid] = p;
    __syncthreads();
    if (threadIdx.x == 0) {
        float s = red[0] + red[1] + red[2] + red[3];
        if (r < NN) sq_s[r] = s; else sq_t[r - NN] = s;
    }
}

// ---------------- kernel 2: bf16 MFMA GEMM (hi/lo 3-term), 2-phase dbuf ------
static __device__ __forceinline__ void stage_tile(const unsigned short* __restrict__ Ab,
                                                  const unsigned short* __restrict__ Bb,
                                                  short* Ad, short* Bd,
                                                  int j0, int i0, int kk,
                                                  int srow, int skoff, int wid) {
#pragma unroll
    for (int r = 0; r < 2; ++r) {
        int row = srow + r * 16;
        const unsigned short* ga = Ab + (size_t)(j0 + row) * DD + kk + skoff;
        __builtin_amdgcn_global_load_lds((const __attribute__((address_space(1))) void*)ga,
                                         (__attribute__((address_space(3))) void*)(Ad + (wid * 2 + r) * 512),
                                         16, 0, 0);
        const unsigned short* gb = Bb + (size_t)(i0 + row) * DD + kk + skoff;
        __builtin_amdgcn_global_load_lds((const __attribute__((address_space(1))) void*)gb,
                                         (__attribute__((address_space(3))) void*)(Bd + (wid * 2 + r) * 512),
                                         16, 0, 0);
    }
}

__global__ __launch_bounds__(256) void gemm_mfma_kernel(
        const unsigned short* __restrict__ tgt_hi, const unsigned short* __restrict__ tgt_lo,
        const unsigned short* __restrict__ src_hi, const unsigned short* __restrict__ src_lo,
        const float* __restrict__ sq_s, const float* __restrict__ sq_t,
        float* __restrict__ simT) {
    __shared__ short Atile[2][128 * 32];  // [row j'][k] 64B/row, double-buffered
    __shared__ short Btile[2][128 * 32];  // [row i'][k]
    int tid = threadIdx.x;
    int wid = tid >> 6, lane = tid & 63;
    int i0 = blockIdx.x * 128;   // source dim
    int j0 = blockIdx.y * 128;   // target dim
    int wr = wid >> 1, wc = wid & 1;

    f32x4 acc[4][4];
#pragma unroll
    for (int m = 0; m < 4; ++m)
#pragma unroll
        for (int n = 0; n < 4; ++n) acc[m][n] = (f32x4){0.f, 0.f, 0.f, 0.f};

    int srow = wid * 32 + (lane >> 2);
    int skoff = (lane & 3) * 8;
    int fr = lane & 15;            // fragment row/col within 16
    int kq = (lane >> 4) * 8;      // fragment k offset

    // t -> (seg, kk): seg selects hi/lo operand pair, kk the 32-wide K slice
    stage_tile(tgt_hi, src_hi, Atile[0], Btile[0], j0, i0, 0, srow, skoff, wid);
    __syncthreads();
    int buf = 0;
    for (int t = 0; t < 24; ++t) {
        if (t < 23) {
            int tn = t + 1;
            int seg = tn >> 3;
            int kk = (tn & 7) * 32;
            const unsigned short* Ab = (seg < 2) ? tgt_hi : tgt_lo;
            const unsigned short* Bb = (seg == 1) ? src_lo : src_hi;
            stage_tile(Ab, Bb, Atile[buf ^ 1], Btile[buf ^ 1], j0, i0, kk, srow, skoff, wid);
        }
        short8 af[4], bfv[4];
#pragma unroll
        for (int m = 0; m < 4; ++m) {
            af[m]  = *(const short8*)(Atile[buf] + (wr * 64 + m * 16 + fr) * 32 + kq);
            bfv[m] = *(const short8*)(Btile[buf] + (wc * 64 + m * 16 + fr) * 32 + kq);
        }
#pragma unroll
        for (int m = 0; m < 4; ++m)
#pragma unroll
            for (int n = 0; n < 4; ++n)
                acc[m][n] = __builtin_amdgcn_mfma_f32_16x16x32_bf16(af[m], bfv[n], acc[m][n], 0, 0, 0);
        __syncthreads();   // drains vmcnt (staged data ready) + protects buf reuse
        buf ^= 1;
    }

    // epilogue: C/D layout col=lane&15 (i), row=(lane>>4)*4+reg (j)
    int fq = lane >> 4;
#pragma unroll
    for (int m = 0; m < 4; ++m) {
#pragma unroll
        for (int n = 0; n < 4; ++n) {
            int i = i0 + wc * 64 + n * 16 + fr;
            float ss = sq_s[i];
#pragma unroll
            for (int r = 0; r < 4; ++r) {
                int j = j0 + wr * 64 + m * 16 + fq * 4 + r;
                float d2 = fmaxf(ss + sq_t[j] - 2.0f * acc[m][n][r], 0.0f);
                simT[(size_t)j * NN + i] = 1.0f / (sqrtf(d2) + 1.0f);
            }
        }
    }
}

// ---------------- kernel 3: per-target top-k vote + score --------------------
// key = bits(v)<<32 | (0xFFFF-idx)<<8 | label : orders (v desc, idx asc), label free.
// 4 waves each own 1024 elems; wave-local top-k via DPP (VALU-only) reduces.
__global__ __launch_bounds__(256) void percol_kernel(const float* __restrict__ simT,
                                                     const int* __restrict__ labels,
                                                     int* __restrict__ assigned,
                                                     float* __restrict__ score) {
    __shared__ u64 f1[4 * KTOP];
    __shared__ u64 f2[4 * MTOP];
    int tid = threadIdx.x, wid = tid >> 6, lane = tid & 63;
    int j = blockIdx.x;
    u64 key[16];
#pragma unroll
    for (int r = 0; r < 16; ++r) {
        int idx = r * 256 + tid;           // wave w owns idx%256 in [w*64,w*64+64)
        float v = simT[(size_t)j * NN + idx];
        int l = labels[idx];
        key[r] = ((u64)__float_as_uint(v) << 32) | ((u64)(u32)(0xFFFFu - (u32)idx) << 8) | (u32)l;
    }

    // ---- phase 1: wave-local top-10 ----
    u64 prev = ~0ull;
    for (int k = 0; k < KTOP; ++k) {
        u64 best = 0;
#pragma unroll
        for (int r = 0; r < 16; ++r) { u64 kk = key[r]; if (kk < prev && kk > best) best = kk; }
        best = wave_max64(best);
        if (lane == 0) f1[wid * KTOP + k] = best;
        prev = best;
    }
    __syncthreads();
    // redundant merge of 40 finalists; lane<31 owns class `lane` for votes
    u64 mk = (lane < 4 * KTOP) ? f1[lane] : 0;
    int votes = 0;
    for (int k = 0; k < KTOP; ++k) {
        u64 b = wave_max64(mk);
        if (mk == b) mk = 0;
        if ((int)(b & 0xFFu) == lane) votes++;
    }
    u32 vk = (lane < NCLS) ? (((u32)votes << 6) | (63u - (u32)lane)) : 0u;
    vk = wave_max32(vk);
    int asg = 63 - (int)(vk & 63u);        // first-max tie-break == jnp.argmax

    // ---- phase 2: top-5 same-label ----
    u64 mk2[16];
#pragma unroll
    for (int r = 0; r < 16; ++r)
        mk2[r] = ((int)(key[r] & 0xFFu) == asg) ? key[r] : (key[r] & 0xFFFFFFFFull);
    prev = ~0ull;
    for (int k = 0; k < MTOP; ++k) {
        u64 best = 0;
#pragma unroll
        for (int r = 0; r < 16; ++r) { u64 kk = mk2[r]; if (kk < prev && kk > best) best = kk; }
        best = wave_max64(best);
        if (lane == 0) f2[wid * MTOP + k] = best;
        prev = best;
    }
    __syncthreads();
    float nln = 0.f;
    {
        u64 m2 = (lane < 4 * MTOP) ? f2[lane] : 0;
        for (int k = 0; k < MTOP; ++k) {
            u64 b = wave_max64(m2);
            if (m2 == b) m2 = 0;
            nln += __uint_as_float((u32)(b >> 32));   // descending order, matches ref sum
        }
    }
    __syncthreads();   // all waves done reading f2 before reuse

    // ---- phase 3: top-5 diff-label ----
#pragma unroll
    for (int r = 0; r < 16; ++r)
        mk2[r] = ((int)(key[r] & 0xFFu) != asg) ? key[r] : (key[r] & 0xFFFFFFFFull);
    prev = ~0ull;
    for (int k = 0; k < MTOP; ++k) {
        u64 best = 0;
#pragma unroll
        for (int r = 0; r < 16; ++r) { u64 kk = mk2[r]; if (kk < prev && kk > best) best = kk; }
        best = wave_max64(best);
        if (lane == 0) f2[wid * MTOP + k] = best;
        prev = best;
    }
    __syncthreads();
    float nun = 0.f;
    {
        u64 m2 = (lane < 4 * MTOP) ? f2[lane] : 0;
        for (int k = 0; k < MTOP; ++k) {
            u64 b = wave_max64(m2);
            if (m2 == b) m2 = 0;
            nun += __uint_as_float((u32)(b >> 32));
        }
    }
    if (tid == 0) {
        assigned[j] = asg;
        score[j] = nln / nun;
    }
}

// ---------------- kernel 4: exact top-MU via radix select --------------------
// Finds the exact MUSEL-th largest u64 key (score desc, idx asc) via 8x 8-bit
// radix passes, then compacts keys >= threshold. Selected SET matches
// lax.top_k exactly; order is arbitrary (downstream is set-invariant).
__global__ __launch_bounds__(1024) void select_kernel(const float* __restrict__ score,
                                                      int* __restrict__ top_tgt) {
    __shared__ u64 keys[NN];        // 32 KB
    __shared__ int hist[256];
    __shared__ u64 s_prefix;
    __shared__ int s_remaining;
    __shared__ int s_counter;
    int tid = threadIdx.x;
    for (int i = tid; i < NN; i += 1024)
        keys[i] = ((u64)__float_as_uint(score[i]) << 32) | (u64)(0xFFFFFFFFu - (u32)i);
    if (tid == 0) { s_prefix = 0; s_remaining = MUSEL; s_counter = 0; }
    __syncthreads();
#pragma unroll
    for (int pass = 0; pass < 8; ++pass) {
        int shift = 56 - pass * 8;
        if (tid < 256) hist[tid] = 0;
        __syncthreads();
        u64 pref = s_prefix;
        for (int i = tid; i < NN; i += 1024) {
            u64 k = keys[i];
            bool match = (pass == 0) || ((k >> (shift + 8)) == (pref >> (shift + 8)));
            if (match) atomicAdd(&hist[(int)((k >> shift) & 0xFF)], 1);
        }
        __syncthreads();
        if (tid == 0) {
            int rem = s_remaining, cum = 0, b = 255;
            for (; b >= 0; --b) {
                if (cum + hist[b] >= rem) break;
                cum += hist[b];
            }
            s_remaining = rem - cum;
            s_prefix = pref | ((u64)(u32)b << shift);
        }
        __syncthreads();
    }
    u64 thr = s_prefix;   // exact MUSEL-th largest key
    for (int i = tid; i < NN; i += 1024) {
        if (keys[i] >= thr) {
            int p = atomicAdd(&s_counter, 1);
            top_tgt[p] = (int)(0xFFFFFFFFu - (u32)(keys[i] & 0xFFFFFFFFull));
        }
    }
}

// ---------------- kernel 5: flab + class histogram ---------------------------
__global__ __launch_bounds__(1024) void flab_kernel(const int* __restrict__ top_tgt,
                                                    const int* __restrict__ assigned,
                                                    int* __restrict__ flab,
                                                    int* __restrict__ hist) {
    __shared__ int h[32];
    int tid = threadIdx.x;
    if (tid < 32) h[tid] = 0;
    __syncthreads();
    for (int r = tid; r < MUSEL; r += 1024) {
        int a = assigned[top_tgt[r]];
        flab[r] = a;
        atomicAdd(&h[a], 1);
    }
    __syncthreads();
    if (tid < 32) hist[tid] = h[tid];
}

// ---------------- kernel 6: softmax partial sums (no max shift needed) -------
// sim in (0,1] so exp(v) <= e: direct sums are exact-equivalent to max-shifted.
#define JCH 128
__global__ __launch_bounds__(256) void fpart_kernel(const float* __restrict__ simT,
                                                    const int* __restrict__ top_tgt,
                                                    const int* __restrict__ flab,
                                                    const int* __restrict__ labels,
                                                    float* __restrict__ ps,
                                                    float* __restrict__ pt) {
    __shared__ int tt[JCH];
    __shared__ int fl[JCH];
    int tid = threadIdx.x;
    int ci = blockIdx.x, cj = blockIdx.y;
    if (tid < JCH) { tt[tid] = top_tgt[cj * JCH + tid]; fl[tid] = flab[cj * JCH + tid]; }
    __syncthreads();
    int i = ci * 256 + tid;
    int myl = labels[i];
    float s = 0.f, t = 0.f;
#pragma unroll 4
    for (int jj = 0; jj < JCH; ++jj) {
        float v = simT[(size_t)tt[jj] * NN + i];
        float e = __expf(v);
        s += e;
        t += (fl[jj] == myl) ? e : 0.f;
    }
    ps[cj * NN + i] = s;
    pt[cj * NN + i] = t;
}

// ---------------- kernel 7: merge partials -> per-block loss partials --------
__global__ __launch_bounds__(256) void merge_kernel(const float* __restrict__ ps,
                                                    const float* __restrict__ pt,
                                                    const int* __restrict__ labels,
                                                    const int* __restrict__ hist,
                                                    float* __restrict__ partials) {
    int tid = threadIdx.x;
    int i = blockIdx.x * 256 + tid;
    float S = 0.f, T = 0.f;
#pragma unroll
    for (int c = 0; c < 16; ++c) {
        S += ps[c * NN + i];
        T += pt[c * NN + i];
    }
    float contr = T / S;
    int ns = hist[labels[i]];
    bool valid = (ns > 0) && (ns < MUSEL);
    float term = valid ? __logf(contr) : 0.0f;
    float cnt = valid ? 1.0f : 0.0f;
    for (int off = 32; off > 0; off >>= 1) {
        term += __shfl_down(term, off);
        cnt  += __shfl_down(cnt, off);
    }
    __shared__ float rt[4], rc[4];
    int wid = tid >> 6, lane = tid & 63;
    if (lane == 0) { rt[wid] = term; rc[wid] = cnt; }
    __syncthreads();
    if (tid == 0) {
        partials[blockIdx.x * 2]     = rt[0] + rt[1] + rt[2] + rt[3];
        partials[blockIdx.x * 2 + 1] = rc[0] + rc[1] + rc[2] + rc[3];
    }
}

// ---------------- kernel 8: final scalar -------------------------------------
__global__ void final_kernel(const float* __restrict__ partials, float* __restrict__ out) {
    if (threadIdx.x == 0) {
        float s = 0.f, c = 0.f;
        for (int b = 0; b < 16; ++b) { s += partials[b * 2]; c += partials[b * 2 + 1]; }
        out[0] = -s / c;
    }
}

extern "C" void kernel_launch(void* const* d_in, const int* in_sizes, int n_in,
                              void* d_out, int out_size, void* d_ws, size_t ws_size,
                              hipStream_t stream) {
    const float* src    = (const float*)d_in[0];
    const int*   labels = (const int*)d_in[1];
    const float* tgt    = (const float*)d_in[2];
    float* out = (float*)d_out;

    char* ws = (char*)d_ws;
    size_t off = 0;
    float* simT = (float*)(ws + off);             off += (size_t)NN * NN * sizeof(float); // 64 MB
    unsigned short* tgt_hi = (unsigned short*)(ws + off); off += (size_t)NN * DD * 2;     // 2 MB
    unsigned short* tgt_lo = (unsigned short*)(ws + off); off += (size_t)NN * DD * 2;
    unsigned short* src_hi = (unsigned short*)(ws + off); off += (size_t)NN * DD * 2;
    unsigned short* src_lo = (unsigned short*)(ws + off); off += (size_t)NN * DD * 2;
    float* sq_s = (float*)(ws + off);      off += NN * sizeof(float);
    float* sq_t = (float*)(ws + off);      off += NN * sizeof(float);
    float* score = (float*)(ws + off);     off += NN * sizeof(float);
    int*   assigned = (int*)(ws + off);    off += NN * sizeof(int);
    int*   top_tgt = (int*)(ws + off);     off += MUSEL * sizeof(int);
    int*   flab = (int*)(ws + off);        off += MUSEL * sizeof(int);
    int*   hist = (int*)(ws + off);        off += 32 * sizeof(int);
    float* partials = (float*)(ws + off);  off += 32 * sizeof(float);
    // ps/pt (256 KB each) alias the dead-after-GEMM bf16 planes
    float* ps = (float*)tgt_lo;
    float* pt = (float*)src_hi;

    conv_kernel<<<(NN * DD) / 256, 256, 0, stream>>>(src, tgt, src_hi, src_lo, tgt_hi, tgt_lo);
    rowsq_kernel<<<2 * NN, 256, 0, stream>>>(src, tgt, sq_s, sq_t);
    gemm_mfma_kernel<<<dim3(NN / 128, NN / 128), 256, 0, stream>>>(tgt_hi, tgt_lo, src_hi, src_lo,
                                                                   sq_s, sq_t, simT);
    percol_kernel<<<NN, 256, 0, stream>>>(simT, labels, assigned, score);
    select_kernel<<<1, 1024, 0, stream>>>(score, top_tgt);
    flab_kernel<<<1, 1024, 0, stream>>>(top_tgt, assigned, flab, hist);
    fpart_kernel<<<dim3(16, 16), 256, 0, stream>>>(simT, top_tgt, flab, labels, ps, pt);
    merge_kernel<<<16, 256, 0, stream>>>(ps, pt, labels, hist, partials);
    final_kernel<<<1, 64, 0, stream>>>(partials, out);
}

// Round 5
// 254.748 us; speedup vs baseline: 1.6670x; 1.0448x over previous
//
#include <hip/hip_runtime.h>
#include <hip/hip_bf16.h>
#include <cfloat>

#define NN 4096
#define DD 256
#define KTOP 10
#define MTOP 5
#define MUSEL 2048
#define NCLS 31

typedef unsigned long long u64;
typedef unsigned int u32;
typedef __attribute__((ext_vector_type(8))) short short8;   // 8 bf16 (4 VGPRs)
typedef __attribute__((ext_vector_type(4))) float f32x4;    // MFMA acc

static __device__ __forceinline__ unsigned short f2bf(float x) {
    u32 u = __float_as_uint(x);
    u32 r = (u + 0x7FFFu + ((u >> 16) & 1u)) >> 16;   // RNE, no NaN inputs here
    return (unsigned short)r;
}
static __device__ __forceinline__ float bf2f(unsigned short h) {
    return __uint_as_float((u32)h << 16);
}

// ---- radix-select pick stage: one wave scans 256-bin hist (suffix from top),
// finds bin b* where cumulative-from-top crosses `need`. Updates prefix/need.
// If total < need (fewer candidates than slots): threshold=0, done=1.
static __device__ __forceinline__ void radix_pick(u32* hist, u32* pref, u32* need,
                                                  u32* done, int shift, int lane) {
    int g = 63 - lane;                       // lane asc == bins desc
    u32 h0 = hist[4 * g + 0], h1 = hist[4 * g + 1];
    u32 h2 = hist[4 * g + 2], h3 = hist[4 * g + 3];
    u32 s = h0 + h1 + h2 + h3;
    u32 P = s;
#pragma unroll
    for (int o = 1; o < 64; o <<= 1) { u32 t = __shfl_up(P, o); if (lane >= o) P += t; }
    u32 nd = *need;
    unsigned long long bal = __ballot(P >= nd);
    if (bal == 0ull) {                       // fewer than `need` candidates total
        if (lane == 0) { *done = 1u; *pref = 0u; *need = 0u; }
        return;
    }
    int l0 = __ffsll(bal) - 1;
    if (lane == l0) {
        u32 c = P - s;                       // count strictly above my 4-bin group
        u32 b;
        if (c + h3 >= nd) b = 3u;
        else { c += h3; if (c + h2 >= nd) b = 2u;
               else { c += h2; if (c + h1 >= nd) b = 1u;
                      else { c += h1; b = 0u; } } }
        *pref |= (u32)(4 * g + (int)b) << shift;
        *need = nd - c;
    }
}

// ---------------- kernel 0: fused fp32->bf16 hi/lo planes + row sq norms -----
__global__ __launch_bounds__(256) void prep_kernel(const float* __restrict__ src,
                                                   const float* __restrict__ tgt,
                                                   unsigned short* __restrict__ src_hi,
                                                   unsigned short* __restrict__ src_lo,
                                                   unsigned short* __restrict__ tgt_hi,
                                                   unsigned short* __restrict__ tgt_lo,
                                                   float* __restrict__ sq_s,
                                                   float* __restrict__ sq_t) {
    int r = blockIdx.x;                      // 0..2N-1
    bool isT = r >= NN;
    int rr = isT ? r - NN : r;
    const float* base = (isT ? tgt : src) + (size_t)rr * DD;
    float x = base[threadIdx.x];
    unsigned short h = f2bf(x);
    unsigned short l = f2bf(x - bf2f(h));
    size_t o = (size_t)rr * DD + threadIdx.x;
    if (isT) { tgt_hi[o] = h; tgt_lo[o] = l; } else { src_hi[o] = h; src_lo[o] = l; }
    float p = x * x;
    for (int off = 32; off > 0; off >>= 1) p += __shfl_down(p, off);
    __shared__ float red[4];
    int wid = threadIdx.x >> 6, lane = threadIdx.x & 63;
    if (lane == 0) red[wid] = p;
    __syncthreads();
    if (threadIdx.x == 0) {
        float s = red[0] + red[1] + red[2] + red[3];
        if (isT) sq_t[rr] = s; else sq_s[rr] = s;
    }
}

// ---------------- kernel 2: bf16 MFMA GEMM (hi/lo 3-term), 2-phase dbuf ------
static __device__ __forceinline__ void stage_tile(const unsigned short* __restrict__ Ab,
                                                  const unsigned short* __restrict__ Bb,
                                                  short* Ad, short* Bd,
                                                  int j0, int i0, int kk,
                                                  int srow, int skoff, int wid) {
#pragma unroll
    for (int r = 0; r < 2; ++r) {
        int row = srow + r * 16;
        const unsigned short* ga = Ab + (size_t)(j0 + row) * DD + kk + skoff;
        __builtin_amdgcn_global_load_lds((const __attribute__((address_space(1))) void*)ga,
                                         (__attribute__((address_space(3))) void*)(Ad + (wid * 2 + r) * 512),
                                         16, 0, 0);
        const unsigned short* gb = Bb + (size_t)(i0 + row) * DD + kk + skoff;
        __builtin_amdgcn_global_load_lds((const __attribute__((address_space(1))) void*)gb,
                                         (__attribute__((address_space(3))) void*)(Bd + (wid * 2 + r) * 512),
                                         16, 0, 0);
    }
}

__global__ __launch_bounds__(256) void gemm_mfma_kernel(
        const unsigned short* __restrict__ tgt_hi, const unsigned short* __restrict__ tgt_lo,
        const unsigned short* __restrict__ src_hi, const unsigned short* __restrict__ src_lo,
        const float* __restrict__ sq_s, const float* __restrict__ sq_t,
        float* __restrict__ simT) {
    __shared__ short Atile[2][128 * 32];
    __shared__ short Btile[2][128 * 32];
    int tid = threadIdx.x;
    int wid = tid >> 6, lane = tid & 63;
    int i0 = blockIdx.x * 128;
    int j0 = blockIdx.y * 128;
    int wr = wid >> 1, wc = wid & 1;

    f32x4 acc[4][4];
#pragma unroll
    for (int m = 0; m < 4; ++m)
#pragma unroll
        for (int n = 0; n < 4; ++n) acc[m][n] = (f32x4){0.f, 0.f, 0.f, 0.f};

    int srow = wid * 32 + (lane >> 2);
    int skoff = (lane & 3) * 8;
    int fr = lane & 15;
    int kq = (lane >> 4) * 8;

    stage_tile(tgt_hi, src_hi, Atile[0], Btile[0], j0, i0, 0, srow, skoff, wid);
    __syncthreads();
    int buf = 0;
    for (int t = 0; t < 24; ++t) {
        if (t < 23) {
            int tn = t + 1;
            int seg = tn >> 3;
            int kk = (tn & 7) * 32;
            const unsigned short* Ab = (seg < 2) ? tgt_hi : tgt_lo;
            const unsigned short* Bb = (seg == 1) ? src_lo : src_hi;
            stage_tile(Ab, Bb, Atile[buf ^ 1], Btile[buf ^ 1], j0, i0, kk, srow, skoff, wid);
        }
        short8 af[4], bfv[4];
#pragma unroll
        for (int m = 0; m < 4; ++m) {
            af[m]  = *(const short8*)(Atile[buf] + (wr * 64 + m * 16 + fr) * 32 + kq);
            bfv[m] = *(const short8*)(Btile[buf] + (wc * 64 + m * 16 + fr) * 32 + kq);
        }
#pragma unroll
        for (int m = 0; m < 4; ++m)
#pragma unroll
            for (int n = 0; n < 4; ++n)
                acc[m][n] = __builtin_amdgcn_mfma_f32_16x16x32_bf16(af[m], bfv[n], acc[m][n], 0, 0, 0);
        __syncthreads();
        buf ^= 1;
    }

    int fq = lane >> 4;
#pragma unroll
    for (int m = 0; m < 4; ++m) {
#pragma unroll
        for (int n = 0; n < 4; ++n) {
            int i = i0 + wc * 64 + n * 16 + fr;
            float ss = sq_s[i];
#pragma unroll
            for (int r = 0; r < 4; ++r) {
                int j = j0 + wr * 64 + m * 16 + fq * 4 + r;
                float d2 = fmaxf(ss + sq_t[j] - 2.0f * acc[m][n][r], 0.0f);
                simT[(size_t)j * NN + i] = 1.0f / (sqrtf(d2) + 1.0f);
            }
        }
    }
}

// ---------------- kernel 3: per-column radix-select top-k + votes + score ----
// Threshold-based: top-10 votes need only {v > v10} labels + smallest-idx ties
// at v == v10; top-5 sums are idx-independent (ties contribute equal values).
// All thresholds exact (full 32-bit radix) => selection sets bit-match lax.top_k.
__global__ __launch_bounds__(256) void percol_kernel(const float* __restrict__ simT,
                                                     const int* __restrict__ labels,
                                                     int* __restrict__ assigned,
                                                     float* __restrict__ score) {
    __shared__ u32 hist2[256];
    __shared__ u32 hist3[256];
    __shared__ u32 votebin[NCLS];
    __shared__ u32 eqlist[64];
    __shared__ u32 s_eqcnt;
    __shared__ u32 s_pref1, s_need1, s_done1;
    __shared__ u32 s_pref2, s_need2, s_done2;
    __shared__ u32 s_pref3, s_need3, s_done3;
    __shared__ int s_asg;
    __shared__ float s_r2[4], s_r3[4];
    int tid = threadIdx.x, lane = tid & 63, wid = tid >> 6;
    int j = blockIdx.x;

    float v[16];
    u32 labp[4] = {0u, 0u, 0u, 0u};
#pragma unroll
    for (int r = 0; r < 16; ++r) {
        int idx = r * 256 + tid;
        v[r] = simT[(size_t)j * NN + idx];
        labp[r >> 2] |= (u32)labels[idx] << ((r & 3) * 8);
    }
#define LAB(r) ((int)((labp[(r) >> 2] >> (((r) & 3) * 8)) & 0xFFu))

    // ---- phase 1: radix-select v10 over all 4096 values ----
    if (tid == 0) { s_pref1 = 0u; s_need1 = KTOP; s_done1 = 0u; }
    hist2[tid] = 0u;
    __syncthreads();
    {   // pass 0 with two-bin per-thread aggregation (values cluster in 1-2 exp bins)
        u32 dA = __float_as_uint(v[0]) >> 24;
        u32 dB = 0xFFFFFFFFu;
        u32 cA = 0u, cB = 0u;
#pragma unroll
        for (int r = 0; r < 16; ++r) {
            u32 dg = __float_as_uint(v[r]) >> 24;
            if (dg == dA) cA++;
            else {
                if (dB == 0xFFFFFFFFu) dB = dg;
                if (dg == dB) cB++;
                else atomicAdd(&hist2[dg], 1u);
            }
        }
        atomicAdd(&hist2[dA], cA);
        if (cB) atomicAdd(&hist2[dB], cB);
    }
    __syncthreads();
    if (wid == 0) radix_pick(hist2, &s_pref1, &s_need1, &s_done1, 24, lane);
    __syncthreads();
    for (int pass = 1; pass < 4; ++pass) {
        int shift = 24 - pass * 8;
        hist2[tid] = 0u;
        __syncthreads();
        u32 pf = s_pref1;
#pragma unroll
        for (int r = 0; r < 16; ++r) {
            u32 b = __float_as_uint(v[r]);
            if ((b >> (shift + 8)) == (pf >> (shift + 8)))
                atomicAdd(&hist2[(b >> shift) & 255u], 1u);
        }
        __syncthreads();
        if (wid == 0) radix_pick(hist2, &s_pref1, &s_need1, &s_done1, shift, lane);
        __syncthreads();
    }
    u32 v10b = s_pref1;
    u32 needeq = s_need1;   // #top-10 slots at exactly v10 (>=1)

    // ---- votes + argmax (first-max tie-break == jnp.argmax) ----
    if (tid < NCLS) votebin[tid] = 0u;
    if (tid == 0) s_eqcnt = 0u;
    __syncthreads();
#pragma unroll
    for (int r = 0; r < 16; ++r) {
        u32 b = __float_as_uint(v[r]);
        if (b > v10b) atomicAdd(&votebin[LAB(r)], 1u);
        else if (b == v10b) {
            u32 p = atomicAdd(&s_eqcnt, 1u);
            if (p < 64u) eqlist[p] = (((u32)(r * 256 + tid)) << 8) | (u32)LAB(r);
        }
    }
    __syncthreads();
    if (tid == 0) {   // boundary: needeq smallest-idx elements at v == v10 vote
        int ne = (int)min(s_eqcnt, 64u);
        for (u32 k = 0; k < needeq; ++k) {
            u32 best = 0xFFFFFFFFu; int bi = -1;
            for (int e = 0; e < ne; ++e)
                if (eqlist[e] < best) { best = eqlist[e]; bi = e; }
            if (bi >= 0) { votebin[best & 0xFFu] += 1u; eqlist[bi] = 0xFFFFFFFFu; }
        }
    }
    __syncthreads();
    if (wid == 0) {
        u32 vk = (lane < NCLS) ? ((votebin[lane] << 6) | (u32)(63 - lane)) : 0u;
#pragma unroll
        for (int o = 1; o < 64; o <<= 1) { u32 t = __shfl_xor(vk, o); vk = vk > t ? vk : t; }
        if (lane == 0) s_asg = 63 - (int)(vk & 63u);
    }
    __syncthreads();
    int asg = s_asg;

    // ---- phases 2/3: shared radix passes for same/diff-label top-5 sums ----
    u32 mmask = 0u;
#pragma unroll
    for (int r = 0; r < 16; ++r) mmask |= (LAB(r) == asg) ? (1u << r) : 0u;

    if (tid == 0) {
        s_pref2 = 0u; s_need2 = MTOP; s_done2 = 0u;
        s_pref3 = 0u; s_need3 = MTOP; s_done3 = 0u;
    }
    hist2[tid] = 0u; hist3[tid] = 0u;
    __syncthreads();
    {   // pass 0, aggregated per stream
        u32 dA2 = 0xFFFFFFFFu, dB2 = 0xFFFFFFFFu, cA2 = 0u, cB2 = 0u;
        u32 dA3 = 0xFFFFFFFFu, dB3 = 0xFFFFFFFFu, cA3 = 0u, cB3 = 0u;
#pragma unroll
        for (int r = 0; r < 16; ++r) {
            u32 dg = __float_as_uint(v[r]) >> 24;
            bool m = (mmask >> r) & 1u;
            if (m) {
                if (dA2 == 0xFFFFFFFFu) dA2 = dg;
                if (dg == dA2) cA2++;
                else { if (dB2 == 0xFFFFFFFFu) dB2 = dg;
                       if (dg == dB2) cB2++; else atomicAdd(&hist2[dg], 1u); }
            } else {
                if (dA3 == 0xFFFFFFFFu) dA3 = dg;
                if (dg == dA3) cA3++;
                else { if (dB3 == 0xFFFFFFFFu) dB3 = dg;
                       if (dg == dB3) cB3++; else atomicAdd(&hist3[dg], 1u); }
            }
        }
        if (cA2) atomicAdd(&hist2[dA2], cA2);
        if (cB2) atomicAdd(&hist2[dB2], cB2);
        if (cA3) atomicAdd(&hist3[dA3], cA3);
        if (cB3) atomicAdd(&hist3[dB3], cB3);
    }
    __syncthreads();
    if (wid == 0) radix_pick(hist2, &s_pref2, &s_need2, &s_done2, 24, lane);
    if (wid == 1) radix_pick(hist3, &s_pref3, &s_need3, &s_done3, 24, lane);
    __syncthreads();
    for (int pass = 1; pass < 4; ++pass) {
        int shift = 24 - pass * 8;
        hist2[tid] = 0u; hist3[tid] = 0u;
        __syncthreads();
        u32 p2 = s_pref2, p3 = s_pref3, d2 = s_done2, d3 = s_done3;
#pragma unroll
        for (int r = 0; r < 16; ++r) {
            u32 b = __float_as_uint(v[r]);
            bool m = (mmask >> r) & 1u;
            if (m) { if (!d2 && (b >> (shift + 8)) == (p2 >> (shift + 8)))
                         atomicAdd(&hist2[(b >> shift) & 255u], 1u); }
            else   { if (!d3 && (b >> (shift + 8)) == (p3 >> (shift + 8)))
                         atomicAdd(&hist3[(b >> shift) & 255u], 1u); }
        }
        __syncthreads();
        if (wid == 0 && !s_done2) radix_pick(hist2, &s_pref2, &s_need2, &s_done2, shift, lane);
        if (wid == 1 && !s_done3) radix_pick(hist3, &s_pref3, &s_need3, &s_done3, shift, lane);
        __syncthreads();
    }
    u32 t2 = s_pref2, ne2 = s_need2;
    u32 t3 = s_pref3, ne3 = s_need3;

    float par2 = 0.f, par3 = 0.f;
#pragma unroll
    for (int r = 0; r < 16; ++r) {
        u32 b = __float_as_uint(v[r]);
        bool m = (mmask >> r) & 1u;
        if (m) { if (b > t2) par2 += v[r]; }
        else   { if (b > t3) par3 += v[r]; }
    }
#pragma unroll
    for (int o = 1; o < 64; o <<= 1) {
        par2 += __shfl_xor(par2, o);
        par3 += __shfl_xor(par3, o);
    }
    if (lane == 0) { s_r2[wid] = par2; s_r3[wid] = par3; }
    __syncthreads();
    if (tid == 0) {
        float nln = s_r2[0] + s_r2[1] + s_r2[2] + s_r2[3] + (float)ne2 * __uint_as_float(t2);
        float nun = s_r3[0] + s_r3[1] + s_r3[2] + s_r3[3] + (float)ne3 * __uint_as_float(t3);
        assigned[j] = asg;
        score[j] = nln / nun;
    }
#undef LAB
}

// ---------------- kernel 4: exact top-MU radix select + flab + class hist ----
__global__ __launch_bounds__(1024) void select_kernel(const float* __restrict__ score,
                                                      const int* __restrict__ assigned,
                                                      int* __restrict__ top_tgt,
                                                      int* __restrict__ flab,
                                                      int* __restrict__ histg) {
    __shared__ u64 keys[NN];        // 32 KB
    __shared__ int hist[256];
    __shared__ int hcls[32];
    __shared__ u64 s_prefix;
    __shared__ int s_remaining;
    __shared__ int s_counter;
    int tid = threadIdx.x;
    for (int i = tid; i < NN; i += 1024)
        keys[i] = ((u64)__float_as_uint(score[i]) << 32) | (u64)(0xFFFFFFFFu - (u32)i);
    if (tid == 0) { s_prefix = 0; s_remaining = MUSEL; s_counter = 0; }
    if (tid < 32) hcls[tid] = 0;
    __syncthreads();
#pragma unroll
    for (int pass = 0; pass < 8; ++pass) {
        int shift = 56 - pass * 8;
        if (tid < 256) hist[tid] = 0;
        __syncthreads();
        u64 pref = s_prefix;
        for (int i = tid; i < NN; i += 1024) {
            u64 k = keys[i];
            bool match = (pass == 0) || ((k >> (shift + 8)) == (pref >> (shift + 8)));
            if (match) atomicAdd(&hist[(int)((k >> shift) & 0xFF)], 1);
        }
        __syncthreads();
        if (tid == 0) {
            int rem = s_remaining, cum = 0, b = 255;
            for (; b >= 0; --b) {
                if (cum + hist[b] >= rem) break;
                cum += hist[b];
            }
            s_remaining = rem - cum;
            s_prefix = pref | ((u64)(u32)b << shift);
        }
        __syncthreads();
    }
    u64 thr = s_prefix;   // exact MUSEL-th largest key
    for (int i = tid; i < NN; i += 1024) {
        if (keys[i] >= thr) {
            int p = atomicAdd(&s_counter, 1);
            int idx = (int)(0xFFFFFFFFu - (u32)(keys[i] & 0xFFFFFFFFull));
            top_tgt[p] = idx;
            int a = assigned[idx];
            flab[p] = a;
            atomicAdd(&hcls[a], 1);
        }
    }
    __syncthreads();
    if (tid < 32) histg[tid] = hcls[tid];
}

// ---------------- kernel 6: softmax partial sums (no max shift needed) -------
#define JCH 128
__global__ __launch_bounds__(256) void fpart_kernel(const float* __restrict__ simT,
                                                    const int* __restrict__ top_tgt,
                                                    const int* __restrict__ flab,
                                                    const int* __restrict__ labels,
                                                    float* __restrict__ ps,
                                                    float* __restrict__ pt) {
    __shared__ int tt[JCH];
    __shared__ int fl[JCH];
    int tid = threadIdx.x;
    int ci = blockIdx.x, cj = blockIdx.y;
    if (tid < JCH) { tt[tid] = top_tgt[cj * JCH + tid]; fl[tid] = flab[cj * JCH + tid]; }
    __syncthreads();
    int i = ci * 256 + tid;
    int myl = labels[i];
    float s = 0.f, t = 0.f;
#pragma unroll 4
    for (int jj = 0; jj < JCH; ++jj) {
        float v = simT[(size_t)tt[jj] * NN + i];
        float e = __expf(v);
        s += e;
        t += (fl[jj] == myl) ? e : 0.f;
    }
    ps[cj * NN + i] = s;
    pt[cj * NN + i] = t;
}

// ---------------- kernel 7: merge partials -> per-block loss partials --------
__global__ __launch_bounds__(256) void merge_kernel(const float* __restrict__ ps,
                                                    const float* __restrict__ pt,
                                                    const int* __restrict__ labels,
                                                    const int* __restrict__ hist,
                                                    float* __restrict__ partials) {
    int tid = threadIdx.x;
    int i = blockIdx.x * 256 + tid;
    float S = 0.f, T = 0.f;
#pragma unroll
    for (int c = 0; c < 16; ++c) {
        S += ps[c * NN + i];
        T += pt[c * NN + i];
    }
    float contr = T / S;
    int ns = hist[labels[i]];
    bool valid = (ns > 0) && (ns < MUSEL);
    float term = valid ? __logf(contr) : 0.0f;
    float cnt = valid ? 1.0f : 0.0f;
    for (int off = 32; off > 0; off >>= 1) {
        term += __shfl_down(term, off);
        cnt  += __shfl_down(cnt, off);
    }
    __shared__ float rt[4], rc[4];
    int wid = tid >> 6, lane = tid & 63;
    if (lane == 0) { rt[wid] = term; rc[wid] = cnt; }
    __syncthreads();
    if (tid == 0) {
        partials[blockIdx.x * 2]     = rt[0] + rt[1] + rt[2] + rt[3];
        partials[blockIdx.x * 2 + 1] = rc[0] + rc[1] + rc[2] + rc[3];
    }
}

// ---------------- kernel 8: final scalar -------------------------------------
__global__ void final_kernel(const float* __restrict__ partials, float* __restrict__ out) {
    if (threadIdx.x == 0) {
        float s = 0.f, c = 0.f;
        for (int b = 0; b < 16; ++b) { s += partials[b * 2]; c += partials[b * 2 + 1]; }
        out[0] = -s / c;
    }
}

extern "C" void kernel_launch(void* const* d_in, const int* in_sizes, int n_in,
                              void* d_out, int out_size, void* d_ws, size_t ws_size,
                              hipStream_t stream) {
    const float* src    = (const float*)d_in[0];
    const int*   labels = (const int*)d_in[1];
    const float* tgt    = (const float*)d_in[2];
    float* out = (float*)d_out;

    char* ws = (char*)d_ws;
    size_t off = 0;
    float* simT = (float*)(ws + off);             off += (size_t)NN * NN * sizeof(float); // 64 MB
    unsigned short* tgt_hi = (unsigned short*)(ws + off); off += (size_t)NN * DD * 2;     // 2 MB
    unsigned short* tgt_lo = (unsigned short*)(ws + off); off += (size_t)NN * DD * 2;
    unsigned short* src_hi = (unsigned short*)(ws + off); off += (size_t)NN * DD * 2;
    unsigned short* src_lo = (unsigned short*)(ws + off); off += (size_t)NN * DD * 2;
    float* sq_s = (float*)(ws + off);      off += NN * sizeof(float);
    float* sq_t = (float*)(ws + off);      off += NN * sizeof(float);
    float* score = (float*)(ws + off);     off += NN * sizeof(float);
    int*   assigned = (int*)(ws + off);    off += NN * sizeof(int);
    int*   top_tgt = (int*)(ws + off);     off += MUSEL * sizeof(int);
    int*   flab = (int*)(ws + off);        off += MUSEL * sizeof(int);
    int*   hist = (int*)(ws + off);        off += 32 * sizeof(int);
    float* partials = (float*)(ws + off);  off += 32 * sizeof(float);
    // ps/pt (256 KB each) alias the dead-after-GEMM bf16 planes
    float* ps = (float*)tgt_lo;
    float* pt = (float*)src_hi;

    prep_kernel<<<2 * NN, 256, 0, stream>>>(src, tgt, src_hi, src_lo, tgt_hi, tgt_lo, sq_s, sq_t);
    gemm_mfma_kernel<<<dim3(NN / 128, NN / 128), 256, 0, stream>>>(tgt_hi, tgt_lo, src_hi, src_lo,
                                                                   sq_s, sq_t, simT);
    percol_kernel<<<NN, 256, 0, stream>>>(simT, labels, assigned, score);
    select_kernel<<<1, 1024, 0, stream>>>(score, assigned, top_tgt, flab, hist);
    fpart_kernel<<<dim3(16, 16), 256, 0, stream>>>(simT, top_tgt, flab, labels, ps, pt);
    merge_kernel<<<16, 256, 0, stream>>>(ps, pt, labels, hist, partials);
    final_kernel<<<1, 64, 0, stream>>>(partials, out);
}

// Round 6
// 239.224 us; speedup vs baseline: 1.7752x; 1.0649x over previous
//
#include <hip/hip_runtime.h>
#include <hip/hip_bf16.h>
#include <cfloat>

#define NN 4096
#define DD 256
#define KTOP 10
#define MTOP 5
#define MUSEL 2048
#define NCLS 31

typedef unsigned long long u64;
typedef unsigned int u32;
typedef __attribute__((ext_vector_type(8))) short short8;   // 8 bf16 (4 VGPRs)
typedef __attribute__((ext_vector_type(4))) float f32x4;    // MFMA acc

static __device__ __forceinline__ unsigned short f2bf(float x) {
    u32 u = __float_as_uint(x);
    u32 r = (u + 0x7FFFu + ((u >> 16) & 1u)) >> 16;   // RNE, no NaN inputs here
    return (unsigned short)r;
}
static __device__ __forceinline__ float bf2f(unsigned short h) {
    return __uint_as_float((u32)h << 16);
}

// wave min/max reduce (result in all lanes)
static __device__ __forceinline__ void wredmm(u32& mn, u32& mx) {
#pragma unroll
    for (int o = 1; o < 64; o <<= 1) {
        u32 a = __shfl_xor(mn, o); mn = a < mn ? a : mn;
        u32 b = __shfl_xor(mx, o); mx = b > mx ? b : mx;
    }
}

// radix pick: one wave scans 256-bin hist (desc), crossing-point of `need`.
// Zeroes the bins it read (ready for next pass). If total < need: done=1,
// pref=0, need=0 ("take all" semantics downstream).
static __device__ __forceinline__ void radix_pick_z(u32* hist, u32* pref, u32* need,
                                                    u32* done, int shift, int lane) {
    int g = 63 - lane;                       // lane asc == bins desc
    u32 h0 = hist[4 * g + 0], h1 = hist[4 * g + 1];
    u32 h2 = hist[4 * g + 2], h3 = hist[4 * g + 3];
    hist[4 * g + 0] = 0u; hist[4 * g + 1] = 0u;
    hist[4 * g + 2] = 0u; hist[4 * g + 3] = 0u;
    u32 s = h0 + h1 + h2 + h3;
    u32 P = s;
#pragma unroll
    for (int o = 1; o < 64; o <<= 1) { u32 t = __shfl_up(P, o); if (lane >= o) P += t; }
    u32 nd = *need;
    unsigned long long bal = __ballot(P >= nd);
    if (bal == 0ull) {
        if (lane == 0) { *done = 1u; *pref = 0u; *need = 0u; }
        return;
    }
    int l0 = __ffsll(bal) - 1;
    if (lane == l0) {
        u32 c = P - s;
        u32 b;
        if (c + h3 >= nd) b = 3u;
        else { c += h3; if (c + h2 >= nd) b = 2u;
               else { c += h2; if (c + h1 >= nd) b = 1u;
                      else { c += h1; b = 0u; } } }
        *pref |= (u32)(4 * g + (int)b) << shift;
        *need = nd - c;
    }
}

// ---------------- kernel 0: fused fp32->bf16 hi/lo planes + row sq norms -----
__global__ __launch_bounds__(256) void prep_kernel(const float* __restrict__ src,
                                                   const float* __restrict__ tgt,
                                                   unsigned short* __restrict__ src_hi,
                                                   unsigned short* __restrict__ src_lo,
                                                   unsigned short* __restrict__ tgt_hi,
                                                   unsigned short* __restrict__ tgt_lo,
                                                   float* __restrict__ sq_s,
                                                   float* __restrict__ sq_t) {
    int r = blockIdx.x;                      // 0..2N-1
    bool isT = r >= NN;
    int rr = isT ? r - NN : r;
    const float* base = (isT ? tgt : src) + (size_t)rr * DD;
    float x = base[threadIdx.x];
    unsigned short h = f2bf(x);
    unsigned short l = f2bf(x - bf2f(h));
    size_t o = (size_t)rr * DD + threadIdx.x;
    if (isT) { tgt_hi[o] = h; tgt_lo[o] = l; } else { src_hi[o] = h; src_lo[o] = l; }
    float p = x * x;
    for (int off = 32; off > 0; off >>= 1) p += __shfl_down(p, off);
    __shared__ float red[4];
    int wid = threadIdx.x >> 6, lane = threadIdx.x & 63;
    if (lane == 0) red[wid] = p;
    __syncthreads();
    if (threadIdx.x == 0) {
        float s = red[0] + red[1] + red[2] + red[3];
        if (isT) sq_t[rr] = s; else sq_s[rr] = s;
    }
}

// ---------------- kernel 2: bf16 MFMA GEMM (hi/lo 3-term), 2-phase dbuf ------
static __device__ __forceinline__ void stage_tile(const unsigned short* __restrict__ Ab,
                                                  const unsigned short* __restrict__ Bb,
                                                  short* Ad, short* Bd,
                                                  int j0, int i0, int kk,
                                                  int srow, int skoff, int wid) {
#pragma unroll
    for (int r = 0; r < 2; ++r) {
        int row = srow + r * 16;
        const unsigned short* ga = Ab + (size_t)(j0 + row) * DD + kk + skoff;
        __builtin_amdgcn_global_load_lds((const __attribute__((address_space(1))) void*)ga,
                                         (__attribute__((address_space(3))) void*)(Ad + (wid * 2 + r) * 512),
                                         16, 0, 0);
        const unsigned short* gb = Bb + (size_t)(i0 + row) * DD + kk + skoff;
        __builtin_amdgcn_global_load_lds((const __attribute__((address_space(1))) void*)gb,
                                         (__attribute__((address_space(3))) void*)(Bd + (wid * 2 + r) * 512),
                                         16, 0, 0);
    }
}

__global__ __launch_bounds__(256) void gemm_mfma_kernel(
        const unsigned short* __restrict__ tgt_hi, const unsigned short* __restrict__ tgt_lo,
        const unsigned short* __restrict__ src_hi, const unsigned short* __restrict__ src_lo,
        const float* __restrict__ sq_s, const float* __restrict__ sq_t,
        float* __restrict__ simT) {
    __shared__ short Atile[2][128 * 32];
    __shared__ short Btile[2][128 * 32];
    int tid = threadIdx.x;
    int wid = tid >> 6, lane = tid & 63;
    // bijective XCD swizzle (1024 blocks % 8 == 0): each XCD gets 128 contiguous
    // logical tiles (4 full j-rows of 32) -> A/B panel reuse lands in its L2.
    int lin = blockIdx.x;
    int wg = (lin & 7) * 128 + (lin >> 3);
    int i0 = (wg & 31) * 128;
    int j0 = (wg >> 5) * 128;
    int wr = wid >> 1, wc = wid & 1;

    f32x4 acc[4][4];
#pragma unroll
    for (int m = 0; m < 4; ++m)
#pragma unroll
        for (int n = 0; n < 4; ++n) acc[m][n] = (f32x4){0.f, 0.f, 0.f, 0.f};

    int srow = wid * 32 + (lane >> 2);
    int skoff = (lane & 3) * 8;
    int fr = lane & 15;
    int kq = (lane >> 4) * 8;

    stage_tile(tgt_hi, src_hi, Atile[0], Btile[0], j0, i0, 0, srow, skoff, wid);
    __syncthreads();
    int buf = 0;
    for (int t = 0; t < 24; ++t) {
        if (t < 23) {
            int tn = t + 1;
            int seg = tn >> 3;
            int kk = (tn & 7) * 32;
            const unsigned short* Ab = (seg < 2) ? tgt_hi : tgt_lo;
            const unsigned short* Bb = (seg == 1) ? src_lo : src_hi;
            stage_tile(Ab, Bb, Atile[buf ^ 1], Btile[buf ^ 1], j0, i0, kk, srow, skoff, wid);
        }
        short8 af[4], bfv[4];
#pragma unroll
        for (int m = 0; m < 4; ++m) {
            af[m]  = *(const short8*)(Atile[buf] + (wr * 64 + m * 16 + fr) * 32 + kq);
            bfv[m] = *(const short8*)(Btile[buf] + (wc * 64 + m * 16 + fr) * 32 + kq);
        }
#pragma unroll
        for (int m = 0; m < 4; ++m)
#pragma unroll
            for (int n = 0; n < 4; ++n)
                acc[m][n] = __builtin_amdgcn_mfma_f32_16x16x32_bf16(af[m], bfv[n], acc[m][n], 0, 0, 0);
        __syncthreads();
        buf ^= 1;
    }

    int fq = lane >> 4;
#pragma unroll
    for (int m = 0; m < 4; ++m) {
#pragma unroll
        for (int n = 0; n < 4; ++n) {
            int i = i0 + wc * 64 + n * 16 + fr;
            float ss = sq_s[i];
#pragma unroll
            for (int r = 0; r < 4; ++r) {
                int j = j0 + wr * 64 + m * 16 + fq * 4 + r;
                float d2 = fmaxf(ss + sq_t[j] - 2.0f * acc[m][n][r], 0.0f);
                simT[(size_t)j * NN + i] = 1.0f / (sqrtf(d2) + 1.0f);
            }
        }
    }
}

// ---------------- kernel 3: per-column radix top-k, 2 columns per block ------
// Streams: 0=ph1-A, 1=ph1-B, 2=A-same, 3=A-diff, 4=B-same, 5=B-diff.
// Pass 0 skipped when all stream values share the top byte (block min/max
// check -- exact); fallback histogram kept for generality.
__global__ __launch_bounds__(256) void percol_kernel(const float* __restrict__ simT,
                                                     const int* __restrict__ labels,
                                                     int* __restrict__ assigned,
                                                     float* __restrict__ score) {
    __shared__ u32 histA2[256], histA3[256], histB2[256], histB3[256];
    __shared__ u32 votebinA[NCLS], votebinB[NCLS];
    __shared__ u32 eqlistA[64], eqlistB[64];
    __shared__ u32 s_eqcntA, s_eqcntB;
    __shared__ u32 s_pref[6], s_need[6], s_done[6];
    __shared__ u32 s_p0mask;
    __shared__ int s_asgA, s_asgB;
    __shared__ u32 s_mm[4][8];
    __shared__ float s_red[4][4];
    int tid = threadIdx.x, lane = tid & 63, wid = tid >> 6;
    int jA = blockIdx.x * 2, jB = jA + 1;

    float vA[16], vB[16];
    u32 labp[4];
    {
        const float4* pA = (const float4*)(simT + (size_t)jA * NN + tid * 16);
        const float4* pB = (const float4*)(simT + (size_t)jB * NN + tid * 16);
        const int4*  pL = (const int4*)(labels + tid * 16);
#pragma unroll
        for (int q = 0; q < 4; ++q) {
            float4 a = pA[q], b = pB[q];
            vA[q * 4 + 0] = a.x; vA[q * 4 + 1] = a.y; vA[q * 4 + 2] = a.z; vA[q * 4 + 3] = a.w;
            vB[q * 4 + 0] = b.x; vB[q * 4 + 1] = b.y; vB[q * 4 + 2] = b.z; vB[q * 4 + 3] = b.w;
            int4 l = pL[q];
            labp[q] = (u32)l.x | ((u32)l.y << 8) | ((u32)l.z << 16) | ((u32)l.w << 24);
        }
    }
#define LAB(r) ((int)((labp[(r) >> 2] >> (((r) & 3) * 8)) & 0xFFu))
    histA2[tid] = 0u; histA3[tid] = 0u; histB2[tid] = 0u; histB3[tid] = 0u;
    if (tid < NCLS) { votebinA[tid] = 0u; votebinB[tid] = 0u; }
    if (tid == 0) { s_eqcntA = 0u; s_eqcntB = 0u; }

    // ---- phase 1: threshold of top-10 (per column) ----
    {
        u32 mnA = ~0u, mxA = 0u, mnB = ~0u, mxB = 0u;
#pragma unroll
        for (int r = 0; r < 16; ++r) {
            u32 a = __float_as_uint(vA[r]); mnA = a < mnA ? a : mnA; mxA = a > mxA ? a : mxA;
            u32 b = __float_as_uint(vB[r]); mnB = b < mnB ? b : mnB; mxB = b > mxB ? b : mxB;
        }
        wredmm(mnA, mxA); wredmm(mnB, mxB);
        if (lane == 0) { s_mm[wid][0] = mnA; s_mm[wid][1] = mxA; s_mm[wid][2] = mnB; s_mm[wid][3] = mxB; }
    }
    __syncthreads();
    if (tid == 0) {
        u32 mn = ~0u, mx = 0u, mn2 = ~0u, mx2 = 0u;
        for (int w = 0; w < 4; ++w) {
            mn = min(mn, s_mm[w][0]); mx = max(mx, s_mm[w][1]);
            mn2 = min(mn2, s_mm[w][2]); mx2 = max(mx2, s_mm[w][3]);
        }
        u32 m0 = 0u;
        s_need[0] = KTOP; s_done[0] = 0u;
        s_need[1] = KTOP; s_done[1] = 0u;
        if ((mn >> 24) == (mx >> 24)) s_pref[0] = mx & 0xFF000000u; else { s_pref[0] = 0u; m0 |= 1u; }
        if ((mn2 >> 24) == (mx2 >> 24)) s_pref[1] = mx2 & 0xFF000000u; else { s_pref[1] = 0u; m0 |= 2u; }
        s_p0mask = m0;
    }
    __syncthreads();
    if (s_p0mask) {      // rare fallback: byte-0 histogram
        u32 m0 = s_p0mask;
#pragma unroll
        for (int r = 0; r < 16; ++r) {
            if (m0 & 1u) atomicAdd(&histA2[__float_as_uint(vA[r]) >> 24], 1u);
            if (m0 & 2u) atomicAdd(&histB2[__float_as_uint(vB[r]) >> 24], 1u);
        }
        __syncthreads();
        if (wid == 0 && (m0 & 1u)) radix_pick_z(histA2, &s_pref[0], &s_need[0], &s_done[0], 24, lane);
        if (wid == 1 && (m0 & 2u)) radix_pick_z(histB2, &s_pref[1], &s_need[1], &s_done[1], 24, lane);
        __syncthreads();
    }
    for (int pass = 1; pass < 4; ++pass) {
        int shift = 24 - pass * 8;
        u32 pA = s_pref[0], pB = s_pref[1];
#pragma unroll
        for (int r = 0; r < 16; ++r) {
            u32 a = __float_as_uint(vA[r]);
            if ((a >> (shift + 8)) == (pA >> (shift + 8))) atomicAdd(&histA2[(a >> shift) & 255u], 1u);
            u32 b = __float_as_uint(vB[r]);
            if ((b >> (shift + 8)) == (pB >> (shift + 8))) atomicAdd(&histB2[(b >> shift) & 255u], 1u);
        }
        __syncthreads();
        if (wid == 0) radix_pick_z(histA2, &s_pref[0], &s_need[0], &s_done[0], shift, lane);
        if (wid == 1) radix_pick_z(histB2, &s_pref[1], &s_need[1], &s_done[1], shift, lane);
        __syncthreads();
    }
    u32 v10A = s_pref[0], neqA = s_need[0];
    u32 v10B = s_pref[1], neqB = s_need[1];

    // ---- votes + argmax (first-max tie-break == jnp.argmax) ----
#pragma unroll
    for (int r = 0; r < 16; ++r) {
        int idx = tid * 16 + r;
        u32 a = __float_as_uint(vA[r]);
        if (a > v10A) atomicAdd(&votebinA[LAB(r)], 1u);
        else if (a == v10A) {
            u32 p = atomicAdd(&s_eqcntA, 1u);
            if (p < 64u) eqlistA[p] = ((u32)idx << 8) | (u32)LAB(r);
        }
        u32 b = __float_as_uint(vB[r]);
        if (b > v10B) atomicAdd(&votebinB[LAB(r)], 1u);
        else if (b == v10B) {
            u32 p = atomicAdd(&s_eqcntB, 1u);
            if (p < 64u) eqlistB[p] = ((u32)idx << 8) | (u32)LAB(r);
        }
    }
    __syncthreads();
    if (tid == 0) {          // boundary ties: neqA smallest-idx at v == v10
        int ne = (int)min(s_eqcntA, 64u);
        for (u32 k = 0; k < neqA; ++k) {
            u32 best = ~0u; int bi = -1;
            for (int e = 0; e < ne; ++e) if (eqlistA[e] < best) { best = eqlistA[e]; bi = e; }
            if (bi >= 0) { votebinA[best & 0xFFu] += 1u; eqlistA[bi] = ~0u; }
        }
    } else if (tid == 64) {
        int ne = (int)min(s_eqcntB, 64u);
        for (u32 k = 0; k < neqB; ++k) {
            u32 best = ~0u; int bi = -1;
            for (int e = 0; e < ne; ++e) if (eqlistB[e] < best) { best = eqlistB[e]; bi = e; }
            if (bi >= 0) { votebinB[best & 0xFFu] += 1u; eqlistB[bi] = ~0u; }
        }
    }
    __syncthreads();
    if (wid == 0) {
        u32 vk = (lane < NCLS) ? ((votebinA[lane] << 6) | (u32)(63 - lane)) : 0u;
#pragma unroll
        for (int o = 1; o < 64; o <<= 1) { u32 t = __shfl_xor(vk, o); vk = vk > t ? vk : t; }
        if (lane == 0) s_asgA = 63 - (int)(vk & 63u);
    } else if (wid == 1) {
        u32 vk = (lane < NCLS) ? ((votebinB[lane] << 6) | (u32)(63 - lane)) : 0u;
#pragma unroll
        for (int o = 1; o < 64; o <<= 1) { u32 t = __shfl_xor(vk, o); vk = vk > t ? vk : t; }
        if (lane == 0) s_asgB = 63 - (int)(vk & 63u);
    }
    __syncthreads();
    int asgA = s_asgA, asgB = s_asgB;

    // ---- phases 2/3: same/diff-label top-5 thresholds, 4 streams ----
    u32 mA = 0u, mB = 0u;
#pragma unroll
    for (int r = 0; r < 16; ++r) {
        if (LAB(r) == asgA) mA |= 1u << r;
        if (LAB(r) == asgB) mB |= 1u << r;
    }
    {
        u32 mn2 = ~0u, mx2 = 0u, mn3 = ~0u, mx3 = 0u;
        u32 mn4 = ~0u, mx4 = 0u, mn5 = ~0u, mx5 = 0u;
#pragma unroll
        for (int r = 0; r < 16; ++r) {
            u32 a = __float_as_uint(vA[r]);
            if ((mA >> r) & 1u) { mn2 = a < mn2 ? a : mn2; mx2 = a > mx2 ? a : mx2; }
            else                { mn3 = a < mn3 ? a : mn3; mx3 = a > mx3 ? a : mx3; }
            u32 b = __float_as_uint(vB[r]);
            if ((mB >> r) & 1u) { mn4 = b < mn4 ? b : mn4; mx4 = b > mx4 ? b : mx4; }
            else                { mn5 = b < mn5 ? b : mn5; mx5 = b > mx5 ? b : mx5; }
        }
        wredmm(mn2, mx2); wredmm(mn3, mx3); wredmm(mn4, mx4); wredmm(mn5, mx5);
        if (lane == 0) {
            s_mm[wid][0] = mn2; s_mm[wid][1] = mx2; s_mm[wid][2] = mn3; s_mm[wid][3] = mx3;
            s_mm[wid][4] = mn4; s_mm[wid][5] = mx4; s_mm[wid][6] = mn5; s_mm[wid][7] = mx5;
        }
    }
    __syncthreads();
    if (tid == 0) {
        u32 m0 = 0u;
        for (int s = 0; s < 4; ++s) {
            u32 mn = ~0u, mx = 0u;
            for (int w = 0; w < 4; ++w) { mn = min(mn, s_mm[w][s * 2]); mx = max(mx, s_mm[w][s * 2 + 1]); }
            int st = 2 + s;
            s_need[st] = MTOP; s_done[st] = 0u;
            if (mx == 0u) { s_pref[st] = 0u; s_done[st] = 1u; s_need[st] = 0u; }  // empty stream
            else if ((mn >> 24) == (mx >> 24)) s_pref[st] = mx & 0xFF000000u;
            else { s_pref[st] = 0u; m0 |= 1u << st; }
        }
        s_p0mask = m0;
    }
    __syncthreads();
    if (s_p0mask) {      // rare fallback
        u32 m0 = s_p0mask;
#pragma unroll
        for (int r = 0; r < 16; ++r) {
            u32 a = __float_as_uint(vA[r]);
            if ((mA >> r) & 1u) { if (m0 & 4u)  atomicAdd(&histA2[a >> 24], 1u); }
            else                { if (m0 & 8u)  atomicAdd(&histA3[a >> 24], 1u); }
            u32 b = __float_as_uint(vB[r]);
            if ((mB >> r) & 1u) { if (m0 & 16u) atomicAdd(&histB2[b >> 24], 1u); }
            else                { if (m0 & 32u) atomicAdd(&histB3[b >> 24], 1u); }
        }
        __syncthreads();
        if (wid == 0 && (m0 & 4u))  radix_pick_z(histA2, &s_pref[2], &s_need[2], &s_done[2], 24, lane);
        if (wid == 1 && (m0 & 8u))  radix_pick_z(histA3, &s_pref[3], &s_need[3], &s_done[3], 24, lane);
        if (wid == 2 && (m0 & 16u)) radix_pick_z(histB2, &s_pref[4], &s_need[4], &s_done[4], 24, lane);
        if (wid == 3 && (m0 & 32u)) radix_pick_z(histB3, &s_pref[5], &s_need[5], &s_done[5], 24, lane);
        __syncthreads();
    }
    for (int pass = 1; pass < 4; ++pass) {
        int shift = 24 - pass * 8;
        u32 p2 = s_pref[2], p3 = s_pref[3], p4 = s_pref[4], p5 = s_pref[5];
        u32 d2 = s_done[2], d3 = s_done[3], d4 = s_done[4], d5 = s_done[5];
#pragma unroll
        for (int r = 0; r < 16; ++r) {
            u32 a = __float_as_uint(vA[r]);
            if ((mA >> r) & 1u) { if (!d2 && (a >> (shift + 8)) == (p2 >> (shift + 8))) atomicAdd(&histA2[(a >> shift) & 255u], 1u); }
            else                { if (!d3 && (a >> (shift + 8)) == (p3 >> (shift + 8))) atomicAdd(&histA3[(a >> shift) & 255u], 1u); }
            u32 b = __float_as_uint(vB[r]);
            if ((mB >> r) & 1u) { if (!d4 && (b >> (shift + 8)) == (p4 >> (shift + 8))) atomicAdd(&histB2[(b >> shift) & 255u], 1u); }
            else                { if (!d5 && (b >> (shift + 8)) == (p5 >> (shift + 8))) atomicAdd(&histB3[(b >> shift) & 255u], 1u); }
        }
        __syncthreads();
        if (wid == 0 && !s_done[2]) radix_pick_z(histA2, &s_pref[2], &s_need[2], &s_done[2], shift, lane);
        if (wid == 1 && !s_done[3]) radix_pick_z(histA3, &s_pref[3], &s_need[3], &s_done[3], shift, lane);
        if (wid == 2 && !s_done[4]) radix_pick_z(histB2, &s_pref[4], &s_need[4], &s_done[4], shift, lane);
        if (wid == 3 && !s_done[5]) radix_pick_z(histB3, &s_pref[5], &s_need[5], &s_done[5], shift, lane);
        __syncthreads();
    }

    // ---- final sums: strictly-greater + boundary-count * threshold ----
    u32 tA2 = s_pref[2], tA3 = s_pref[3], tB2 = s_pref[4], tB3 = s_pref[5];
    float pA2 = 0.f, pA3 = 0.f, pB2 = 0.f, pB3 = 0.f;
#pragma unroll
    for (int r = 0; r < 16; ++r) {
        u32 a = __float_as_uint(vA[r]);
        if ((mA >> r) & 1u) { if (a > tA2) pA2 += vA[r]; }
        else                { if (a > tA3) pA3 += vA[r]; }
        u32 b = __float_as_uint(vB[r]);
        if ((mB >> r) & 1u) { if (b > tB2) pB2 += vB[r]; }
        else                { if (b > tB3) pB3 += vB[r]; }
    }
#pragma unroll
    for (int o = 1; o < 64; o <<= 1) {
        pA2 += __shfl_xor(pA2, o);
        pA3 += __shfl_xor(pA3, o);
        pB2 += __shfl_xor(pB2, o);
        pB3 += __shfl_xor(pB3, o);
    }
    if (lane == 0) { s_red[wid][0] = pA2; s_red[wid][1] = pA3; s_red[wid][2] = pB2; s_red[wid][3] = pB3; }
    __syncthreads();
    if (tid == 0) {
        float nln = s_red[0][0] + s_red[1][0] + s_red[2][0] + s_red[3][0]
                  + (float)s_need[2] * __uint_as_float(s_pref[2]);
        float nun = s_red[0][1] + s_red[1][1] + s_red[2][1] + s_red[3][1]
                  + (float)s_need[3] * __uint_as_float(s_pref[3]);
        assigned[jA] = asgA;
        score[jA] = nln / nun;
    } else if (tid == 64) {
        float nln = s_red[0][2] + s_red[1][2] + s_red[2][2] + s_red[3][2]
                  + (float)s_need[4] * __uint_as_float(s_pref[4]);
        float nun = s_red[0][3] + s_red[1][3] + s_red[2][3] + s_red[3][3]
                  + (float)s_need[5] * __uint_as_float(s_pref[5]);
        assigned[jB] = asgB;
        score[jB] = nln / nun;
    }
#undef LAB
}

// ---------------- kernel 4: exact top-MU radix select + flab + class hist ----
__global__ __launch_bounds__(1024) void select_kernel(const float* __restrict__ score,
                                                      const int* __restrict__ assigned,
                                                      int* __restrict__ top_tgt,
                                                      int* __restrict__ flab,
                                                      int* __restrict__ histg) {
    __shared__ u64 keys[NN];        // 32 KB
    __shared__ int hist[256];
    __shared__ int hcls[32];
    __shared__ u64 s_prefix;
    __shared__ int s_remaining;
    __shared__ int s_counter;
    int tid = threadIdx.x;
    for (int i = tid; i < NN; i += 1024)
        keys[i] = ((u64)__float_as_uint(score[i]) << 32) | (u64)(0xFFFFFFFFu - (u32)i);
    if (tid == 0) { s_prefix = 0; s_remaining = MUSEL; s_counter = 0; }
    if (tid < 32) hcls[tid] = 0;
    __syncthreads();
#pragma unroll
    for (int pass = 0; pass < 8; ++pass) {
        int shift = 56 - pass * 8;
        if (tid < 256) hist[tid] = 0;
        __syncthreads();
        u64 pref = s_prefix;
        for (int i = tid; i < NN; i += 1024) {
            u64 k = keys[i];
            bool match = (pass == 0) || ((k >> (shift + 8)) == (pref >> (shift + 8)));
            if (match) atomicAdd(&hist[(int)((k >> shift) & 0xFF)], 1);
        }
        __syncthreads();
        if (tid == 0) {
            int rem = s_remaining, cum = 0, b = 255;
            for (; b >= 0; --b) {
                if (cum + hist[b] >= rem) break;
                cum += hist[b];
            }
            s_remaining = rem - cum;
            s_prefix = pref | ((u64)(u32)b << shift);
        }
        __syncthreads();
    }
    u64 thr = s_prefix;   // exact MUSEL-th largest key
    for (int i = tid; i < NN; i += 1024) {
        if (keys[i] >= thr) {
            int p = atomicAdd(&s_counter, 1);
            int idx = (int)(0xFFFFFFFFu - (u32)(keys[i] & 0xFFFFFFFFull));
            top_tgt[p] = idx;
            int a = assigned[idx];
            flab[p] = a;
            atomicAdd(&hcls[a], 1);
        }
    }
    __syncthreads();
    if (tid < 32) histg[tid] = hcls[tid];
}

// ---------------- kernel 6: softmax partial sums (no max shift needed) -------
// sim in (0,1] so exp(v) <= e: direct sums exact-equivalent to max-shifted.
#define JCH 64
__global__ __launch_bounds__(256) void fpart_kernel(const float* __restrict__ simT,
                                                    const int* __restrict__ top_tgt,
                                                    const int* __restrict__ flab,
                                                    const int* __restrict__ labels,
                                                    float* __restrict__ ps,
                                                    float* __restrict__ pt) {
    __shared__ int tt[JCH];
    __shared__ int fl[JCH];
    int tid = threadIdx.x;
    int ci = blockIdx.x, cj = blockIdx.y;
    if (tid < JCH) { tt[tid] = top_tgt[cj * JCH + tid]; fl[tid] = flab[cj * JCH + tid]; }
    __syncthreads();
    int i = ci * 256 + tid;
    int myl = labels[i];
    float s = 0.f, t = 0.f;
#pragma unroll 4
    for (int jj = 0; jj < JCH; ++jj) {
        float v = simT[(size_t)tt[jj] * NN + i];
        float e = __expf(v);
        s += e;
        t += (fl[jj] == myl) ? e : 0.f;
    }
    ps[cj * NN + i] = s;
    pt[cj * NN + i] = t;
}

// ---------------- kernel 7: merge partials -> per-block loss partials --------
__global__ __launch_bounds__(256) void merge_kernel(const float* __restrict__ ps,
                                                    const float* __restrict__ pt,
                                                    const int* __restrict__ labels,
                                                    const int* __restrict__ hist,
                                                    float* __restrict__ partials) {
    int tid = threadIdx.x;
    int i = blockIdx.x * 256 + tid;
    float S = 0.f, T = 0.f;
#pragma unroll
    for (int c = 0; c < 32; ++c) {
        S += ps[c * NN + i];
        T += pt[c * NN + i];
    }
    float contr = T / S;
    int ns = hist[labels[i]];
    bool valid = (ns > 0) && (ns < MUSEL);
    float term = valid ? __logf(contr) : 0.0f;
    float cnt = valid ? 1.0f : 0.0f;
    for (int off = 32; off > 0; off >>= 1) {
        term += __shfl_down(term, off);
        cnt  += __shfl_down(cnt, off);
    }
    __shared__ float rt[4], rc[4];
    int wid = tid >> 6, lane = tid & 63;
    if (lane == 0) { rt[wid] = term; rc[wid] = cnt; }
    __syncthreads();
    if (tid == 0) {
        partials[blockIdx.x * 2]     = rt[0] + rt[1] + rt[2] + rt[3];
        partials[blockIdx.x * 2 + 1] = rc[0] + rc[1] + rc[2] + rc[3];
    }
}

// ---------------- kernel 8: final scalar -------------------------------------
__global__ void final_kernel(const float* __restrict__ partials, float* __restrict__ out) {
    if (threadIdx.x == 0) {
        float s = 0.f, c = 0.f;
        for (int b = 0; b < 16; ++b) { s += partials[b * 2]; c += partials[b * 2 + 1]; }
        out[0] = -s / c;
    }
}

extern "C" void kernel_launch(void* const* d_in, const int* in_sizes, int n_in,
                              void* d_out, int out_size, void* d_ws, size_t ws_size,
                              hipStream_t stream) {
    const float* src    = (const float*)d_in[0];
    const int*   labels = (const int*)d_in[1];
    const float* tgt    = (const float*)d_in[2];
    float* out = (float*)d_out;

    char* ws = (char*)d_ws;
    size_t off = 0;
    float* simT = (float*)(ws + off);             off += (size_t)NN * NN * sizeof(float); // 64 MB
    unsigned short* tgt_hi = (unsigned short*)(ws + off); off += (size_t)NN * DD * 2;     // 2 MB
    unsigned short* tgt_lo = (unsigned short*)(ws + off); off += (size_t)NN * DD * 2;
    unsigned short* src_hi = (unsigned short*)(ws + off); off += (size_t)NN * DD * 2;
    unsigned short* src_lo = (unsigned short*)(ws + off); off += (size_t)NN * DD * 2;
    float* sq_s = (float*)(ws + off);      off += NN * sizeof(float);
    float* sq_t = (float*)(ws + off);      off += NN * sizeof(float);
    float* score = (float*)(ws + off);     off += NN * sizeof(float);
    int*   assigned = (int*)(ws + off);    off += NN * sizeof(int);
    int*   top_tgt = (int*)(ws + off);     off += MUSEL * sizeof(int);
    int*   flab = (int*)(ws + off);        off += MUSEL * sizeof(int);
    int*   hist = (int*)(ws + off);        off += 32 * sizeof(int);
    float* partials = (float*)(ws + off);  off += 32 * sizeof(float);
    // ps/pt (512 KB each) alias the dead-after-GEMM bf16 planes (2 MB each)
    float* ps = (float*)tgt_lo;
    float* pt = (float*)src_hi;

    prep_kernel<<<2 * NN, 256, 0, stream>>>(src, tgt, src_hi, src_lo, tgt_hi, tgt_lo, sq_s, sq_t);
    gemm_mfma_kernel<<<1024, 256, 0, stream>>>(tgt_hi, tgt_lo, src_hi, src_lo, sq_s, sq_t, simT);
    percol_kernel<<<NN / 2, 256, 0, stream>>>(simT, labels, assigned, score);
    select_kernel<<<1, 1024, 0, stream>>>(score, assigned, top_tgt, flab, hist);
    fpart_kernel<<<dim3(16, 32), 256, 0, stream>>>(simT, top_tgt, flab, labels, ps, pt);
    merge_kernel<<<16, 256, 0, stream>>>(ps, pt, labels, hist, partials);
    final_kernel<<<1, 64, 0, stream>>>(partials, out);
}

// Round 8
// 234.150 us; speedup vs baseline: 1.8137x; 1.0217x over previous
//
#include <hip/hip_runtime.h>
#include <hip/hip_bf16.h>
#include <cfloat>

#define NN 4096
#define DD 256
#define KTOP 10
#define MTOP 5
#define MUSEL 2048
#define NCLS 31

typedef unsigned long long u64;
typedef unsigned int u32;
typedef __attribute__((ext_vector_type(8))) short short8;   // 8 bf16 (4 VGPRs)
typedef __attribute__((ext_vector_type(4))) float f32x4;    // MFMA acc

static __device__ __forceinline__ unsigned short f2bf(float x) {
    u32 u = __float_as_uint(x);
    u32 r = (u + 0x7FFFu + ((u >> 16) & 1u)) >> 16;   // RNE, no NaN inputs here
    return (unsigned short)r;
}
static __device__ __forceinline__ float bf2f(unsigned short h) {
    return __uint_as_float((u32)h << 16);
}

// ---- DPP wave reductions (canonical row_shr/row_bcast sequence, result lane63,
// broadcast via readlane -> wave-uniform SGPR). Validated on HW in round 4.
template <int C>
static __device__ __forceinline__ u32 dpp_keep(u32 x) {   // invalid lanes keep old
    return (u32)__builtin_amdgcn_update_dpp((int)x, (int)x, C, 0xF, 0xF, false);
}
template <int C>
static __device__ __forceinline__ u32 dpp_zero(u32 x) {   // invalid lanes -> 0
    return (u32)__builtin_amdgcn_update_dpp(0, (int)x, C, 0xF, 0xF, true);
}
static __device__ __forceinline__ u32 wred_max(u32 x) {
#define S(C) { u32 t = dpp_keep<C>(x); x = t > x ? t : x; }
    S(0x111) S(0x112) S(0x114) S(0x118) S(0x142) S(0x143)
#undef S
    return (u32)__builtin_amdgcn_readlane((int)x, 63);
}
static __device__ __forceinline__ u32 wred_min(u32 x) {
#define S(C) { u32 t = dpp_keep<C>(x); x = t < x ? t : x; }
    S(0x111) S(0x112) S(0x114) S(0x118) S(0x142) S(0x143)
#undef S
    return (u32)__builtin_amdgcn_readlane((int)x, 63);
}
static __device__ __forceinline__ float wred_sumf(float x) {
#define S(C) { u32 t = dpp_zero<C>(__float_as_uint(x)); x += __uint_as_float(t); }
    S(0x111) S(0x112) S(0x114) S(0x118) S(0x142) S(0x143)
#undef S
    return __uint_as_float((u32)__builtin_amdgcn_readlane((int)__float_as_uint(x), 63));
}

// ---- wave-local radix pick: wave-private 256-bin hist (zeroed on read),
// state (pref/need/done) in wave-uniform registers. No barriers: same-wave
// LDS ops complete in program order.
static __device__ __forceinline__ void wpick(u32* hist, u32& pref, u32& need,
                                             u32& done, int shift, int lane) {
    if (done) return;                         // wave-uniform
    int g = 63 - lane;                        // lane asc == bins desc
    uint4 h = *(uint4*)&hist[4 * g];
    *(uint4*)&hist[4 * g] = make_uint4(0u, 0u, 0u, 0u);
    u32 s = h.x + h.y + h.z + h.w;
    u32 P = s;
#pragma unroll
    for (int o = 1; o < 64; o <<= 1) { u32 t = __shfl_up(P, o); if (lane >= o) P += t; }
    unsigned long long bal = __ballot(P >= need);
    if (bal == 0ull) { done = 1u; pref = 0u; need = 0u; return; }
    int l0 = __ffsll(bal) - 1;
    u32 c = P - s, b, nn;
    if (c + h.w >= need) { b = 3u; nn = need - c; }
    else { c += h.w; if (c + h.z >= need) { b = 2u; nn = need - c; }
           else { c += h.z; if (c + h.y >= need) { b = 1u; nn = need - c; }
                  else { c += h.y; b = 0u; nn = need - c; } } }
    u32 bin = (u32)(4 * g) + b;
    bin = (u32)__shfl((int)bin, l0);
    nn  = (u32)__shfl((int)nn, l0);
    pref |= bin << shift;
    need = nn;
}

// ---------------- kernel 0: fused fp32->bf16 hi/lo planes + row sq norms -----
__global__ __launch_bounds__(256) void prep_kernel(const float* __restrict__ src,
                                                   const float* __restrict__ tgt,
                                                   unsigned short* __restrict__ src_hi,
                                                   unsigned short* __restrict__ src_lo,
                                                   unsigned short* __restrict__ tgt_hi,
                                                   unsigned short* __restrict__ tgt_lo,
                                                   float* __restrict__ sq_s,
                                                   float* __restrict__ sq_t) {
    int r = blockIdx.x;                      // 0..2N-1
    bool isT = r >= NN;
    int rr = isT ? r - NN : r;
    const float* base = (isT ? tgt : src) + (size_t)rr * DD;
    float x = base[threadIdx.x];
    unsigned short h = f2bf(x);
    unsigned short l = f2bf(x - bf2f(h));
    size_t o = (size_t)rr * DD + threadIdx.x;
    if (isT) { tgt_hi[o] = h; tgt_lo[o] = l; } else { src_hi[o] = h; src_lo[o] = l; }
    float p = x * x;
    for (int off = 32; off > 0; off >>= 1) p += __shfl_down(p, off);
    __shared__ float red[4];
    int wid = threadIdx.x >> 6, lane = threadIdx.x & 63;
    if (lane == 0) red[wid] = p;
    __syncthreads();
    if (threadIdx.x == 0) {
        float s = red[0] + red[1] + red[2] + red[3];
        if (isT) sq_t[rr] = s; else sq_s[rr] = s;
    }
}

// ---------------- kernel 2: bf16 MFMA GEMM (hi/lo 3-term), 2-phase dbuf ------
static __device__ __forceinline__ void stage_tile(const unsigned short* __restrict__ Ab,
                                                  const unsigned short* __restrict__ Bb,
                                                  short* Ad, short* Bd,
                                                  int j0, int i0, int kk,
                                                  int srow, int skoff, int wid) {
#pragma unroll
    for (int r = 0; r < 2; ++r) {
        int row = srow + r * 16;
        const unsigned short* ga = Ab + (size_t)(j0 + row) * DD + kk + skoff;
        __builtin_amdgcn_global_load_lds((const __attribute__((address_space(1))) void*)ga,
                                         (__attribute__((address_space(3))) void*)(Ad + (wid * 2 + r) * 512),
                                         16, 0, 0);
        const unsigned short* gb = Bb + (size_t)(i0 + row) * DD + kk + skoff;
        __builtin_amdgcn_global_load_lds((const __attribute__((address_space(1))) void*)gb,
                                         (__attribute__((address_space(3))) void*)(Bd + (wid * 2 + r) * 512),
                                         16, 0, 0);
    }
}

__global__ __launch_bounds__(256) void gemm_mfma_kernel(
        const unsigned short* __restrict__ tgt_hi, const unsigned short* __restrict__ tgt_lo,
        const unsigned short* __restrict__ src_hi, const unsigned short* __restrict__ src_lo,
        const float* __restrict__ sq_s, const float* __restrict__ sq_t,
        float* __restrict__ simT) {
    __shared__ short Atile[2][128 * 32];
    __shared__ short Btile[2][128 * 32];
    int tid = threadIdx.x;
    int wid = tid >> 6, lane = tid & 63;
    // bijective XCD swizzle (1024 blocks % 8 == 0)
    int lin = blockIdx.x;
    int wg = (lin & 7) * 128 + (lin >> 3);
    int i0 = (wg & 31) * 128;
    int j0 = (wg >> 5) * 128;
    int wr = wid >> 1, wc = wid & 1;

    f32x4 acc[4][4];
#pragma unroll
    for (int m = 0; m < 4; ++m)
#pragma unroll
        for (int n = 0; n < 4; ++n) acc[m][n] = (f32x4){0.f, 0.f, 0.f, 0.f};

    int srow = wid * 32 + (lane >> 2);
    int skoff = (lane & 3) * 8;
    int fr = lane & 15;
    int kq = (lane >> 4) * 8;

    stage_tile(tgt_hi, src_hi, Atile[0], Btile[0], j0, i0, 0, srow, skoff, wid);
    __syncthreads();
    int buf = 0;
    for (int t = 0; t < 24; ++t) {
        if (t < 23) {
            int tn = t + 1;
            int seg = tn >> 3;
            int kk = (tn & 7) * 32;
            const unsigned short* Ab = (seg < 2) ? tgt_hi : tgt_lo;
            const unsigned short* Bb = (seg == 1) ? src_lo : src_hi;
            stage_tile(Ab, Bb, Atile[buf ^ 1], Btile[buf ^ 1], j0, i0, kk, srow, skoff, wid);
        }
        short8 af[4], bfv[4];
#pragma unroll
        for (int m = 0; m < 4; ++m) {
            af[m]  = *(const short8*)(Atile[buf] + (wr * 64 + m * 16 + fr) * 32 + kq);
            bfv[m] = *(const short8*)(Btile[buf] + (wc * 64 + m * 16 + fr) * 32 + kq);
        }
#pragma unroll
        for (int m = 0; m < 4; ++m)
#pragma unroll
            for (int n = 0; n < 4; ++n)
                acc[m][n] = __builtin_amdgcn_mfma_f32_16x16x32_bf16(af[m], bfv[n], acc[m][n], 0, 0, 0);
        __syncthreads();
        buf ^= 1;
    }

    int fq = lane >> 4;
#pragma unroll
    for (int m = 0; m < 4; ++m) {
#pragma unroll
        for (int n = 0; n < 4; ++n) {
            int i = i0 + wc * 64 + n * 16 + fr;
            float ss = sq_s[i];
#pragma unroll
            for (int r = 0; r < 4; ++r) {
                int j = j0 + wr * 64 + m * 16 + fq * 4 + r;
                float d2 = fmaxf(ss + sq_t[j] - 2.0f * acc[m][n][r], 0.0f);
                simT[(size_t)j * NN + i] = 1.0f / (sqrtf(d2) + 1.0f);
            }
        }
    }
}

// ---------------- kernel 3: percol, ONE WAVE PER COLUMN, zero barriers -------
// Each 128-thr block = 2 independent waves, each owns one column + wave-private
// LDS. Same-wave LDS ops are program-ordered => no __syncthreads anywhere.
// All selections threshold-based (exact 32-bit radix): identical sets to
// lax.top_k; boundary ties handled by count (sums) / smallest-idx (votes).
__global__ __launch_bounds__(128, 2) void percol_kernel(const float* __restrict__ simT,
                                                        const int* __restrict__ labels,
                                                        int* __restrict__ assigned,
                                                        float* __restrict__ score) {
    __shared__ __attribute__((aligned(16))) u32 hist2s[2][256];
    __shared__ __attribute__((aligned(16))) u32 hist3s[2][256];
    __shared__ u32 votebins[2][32];
    __shared__ u32 eqlists[2][64];
    __shared__ u32 eqcnts[2];
    int tid = threadIdx.x, lane = tid & 63, wid = tid >> 6;
    int j = blockIdx.x * 2 + wid;
    u32* h2 = hist2s[wid];
    u32* h3 = hist3s[wid];
    u32* vb = votebins[wid];
    u32* eql = eqlists[wid];

    float v[64];
    u32 labp[16];
#pragma unroll
    for (int q = 0; q < 16; ++q) {
        float4 a = *(const float4*)(simT + (size_t)j * NN + q * 256 + lane * 4);
        v[q * 4 + 0] = a.x; v[q * 4 + 1] = a.y; v[q * 4 + 2] = a.z; v[q * 4 + 3] = a.w;
        int4 L = *(const int4*)(labels + q * 256 + lane * 4);
        labp[q] = (u32)L.x | ((u32)L.y << 8) | ((u32)L.z << 16) | ((u32)L.w << 24);
    }
#define LPW(r) ((int)((labp[(r) >> 2] >> (((r) & 3) * 8)) & 0xFFu))
    // zero wave-private LDS (ordered before first atomic use within this wave)
#pragma unroll
    for (int t = 0; t < 4; ++t) { h2[lane + t * 64] = 0u; h3[lane + t * 64] = 0u; }
    if (lane < 32) vb[lane] = 0u;
    if (lane == 0) eqcnts[wid] = 0u;

    // ---- phase 1: exact v10 threshold ----
    u32 mn = ~0u, mx = 0u;
#pragma unroll
    for (int r = 0; r < 64; ++r) {
        u32 b = __float_as_uint(v[r]);
        mn = b < mn ? b : mn; mx = b > mx ? b : mx;
    }
    mn = wred_min(mn); mx = wred_max(mx);

    u32 pref1, need1 = KTOP, done1 = 0u;
    if ((mn >> 24) == (mx >> 24)) pref1 = mx & 0xFF000000u;
    else {
        pref1 = 0u;
#pragma unroll
        for (int r = 0; r < 64; ++r) atomicAdd(&h2[__float_as_uint(v[r]) >> 24], 1u);
        wpick(h2, pref1, need1, done1, 24, lane);
    }
#pragma unroll
    for (int r = 0; r < 64; ++r) {
        u32 b = __float_as_uint(v[r]);
        if ((b >> 24) == (pref1 >> 24)) atomicAdd(&h2[(b >> 16) & 255u], 1u);
    }
    wpick(h2, pref1, need1, done1, 16, lane);
#pragma unroll
    for (int r = 0; r < 64; ++r) {
        u32 b = __float_as_uint(v[r]);
        if ((b >> 16) == (pref1 >> 16)) atomicAdd(&h2[(b >> 8) & 255u], 1u);
    }
    wpick(h2, pref1, need1, done1, 8, lane);
#pragma unroll
    for (int r = 0; r < 64; ++r) {
        u32 b = __float_as_uint(v[r]);
        if ((b >> 8) == (pref1 >> 8)) atomicAdd(&h2[b & 255u], 1u);
    }
    wpick(h2, pref1, need1, done1, 0, lane);
    u32 v10 = pref1, neq = need1;

    // ---- votes + argmax (first-max tie-break == jnp.argmax) ----
#pragma unroll
    for (int r = 0; r < 64; ++r) {
        u32 b = __float_as_uint(v[r]);
        if (b > v10) atomicAdd(&vb[LPW(r)], 1u);
        else if (b == v10) {
            u32 p = atomicAdd(&eqcnts[wid], 1u);
            if (p < 64u)
                eql[p] = ((u32)((r >> 2) * 256 + lane * 4 + (r & 3)) << 8) | (u32)LPW(r);
        }
    }
    if (lane == 0) {                 // boundary: neq smallest-idx ties vote
        int ne = (int)min(eqcnts[wid], 64u);
        for (u32 k = 0; k < neq; ++k) {
            u32 best = ~0u; int bi = -1;
            for (int e = 0; e < ne; ++e) if (eql[e] < best) { best = eql[e]; bi = e; }
            if (bi >= 0) { vb[best & 0xFFu] += 1u; eql[bi] = ~0u; }
        }
    }
    u32 vk = (lane < NCLS) ? ((vb[lane] << 6) | (u32)(63 - lane)) : 0u;
    vk = wred_max(vk);
    int asg = 63 - (int)(vk & 63u);

    // ---- phases 2/3: same/diff-label exact top-5 thresholds ----
    u64 sm = 0ull;
#pragma unroll
    for (int r = 0; r < 64; ++r) if (LPW(r) == asg) sm |= 1ull << r;

    u32 mn2 = ~0u, mx2 = 0u, mn3 = ~0u, mx3 = 0u;
#pragma unroll
    for (int r = 0; r < 64; ++r) {
        u32 b = __float_as_uint(v[r]);
        if ((sm >> r) & 1ull) { mn2 = b < mn2 ? b : mn2; mx2 = b > mx2 ? b : mx2; }
        else                  { mn3 = b < mn3 ? b : mn3; mx3 = b > mx3 ? b : mx3; }
    }
    mn2 = wred_min(mn2); mx2 = wred_max(mx2);
    mn3 = wred_min(mn3); mx3 = wred_max(mx3);

    u32 pref2, need2 = MTOP, done2 = 0u;
    u32 pref3, need3 = MTOP, done3 = 0u;
    bool fb2 = false, fb3 = false;
    if (mx2 == 0u) { pref2 = 0u; need2 = 0u; done2 = 1u; }         // empty stream
    else if ((mn2 >> 24) == (mx2 >> 24)) pref2 = mx2 & 0xFF000000u;
    else { pref2 = 0u; fb2 = true; }
    if (mx3 == 0u) { pref3 = 0u; need3 = 0u; done3 = 1u; }
    else if ((mn3 >> 24) == (mx3 >> 24)) pref3 = mx3 & 0xFF000000u;
    else { pref3 = 0u; fb3 = true; }

    if (fb2 || fb3) {
#pragma unroll
        for (int r = 0; r < 64; ++r) {
            u32 b = __float_as_uint(v[r]);
            if ((sm >> r) & 1ull) { if (fb2) atomicAdd(&h2[b >> 24], 1u); }
            else                  { if (fb3) atomicAdd(&h3[b >> 24], 1u); }
        }
        if (fb2) wpick(h2, pref2, need2, done2, 24, lane);
        if (fb3) wpick(h3, pref3, need3, done3, 24, lane);
    }
#pragma unroll
    for (int r = 0; r < 64; ++r) {
        u32 b = __float_as_uint(v[r]);
        if ((sm >> r) & 1ull) { if (!done2 && (b >> 24) == (pref2 >> 24)) atomicAdd(&h2[(b >> 16) & 255u], 1u); }
        else                  { if (!done3 && (b >> 24) == (pref3 >> 24)) atomicAdd(&h3[(b >> 16) & 255u], 1u); }
    }
    wpick(h2, pref2, need2, done2, 16, lane);
    wpick(h3, pref3, need3, done3, 16, lane);
#pragma unroll
    for (int r = 0; r < 64; ++r) {
        u32 b = __float_as_uint(v[r]);
        if ((sm >> r) & 1ull) { if (!done2 && (b >> 16) == (pref2 >> 16)) atomicAdd(&h2[(b >> 8) & 255u], 1u); }
        else                  { if (!done3 && (b >> 16) == (pref3 >> 16)) atomicAdd(&h3[(b >> 8) & 255u], 1u); }
    }
    wpick(h2, pref2, need2, done2, 8, lane);
    wpick(h3, pref3, need3, done3, 8, lane);
#pragma unroll
    for (int r = 0; r < 64; ++r) {
        u32 b = __float_as_uint(v[r]);
        if ((sm >> r) & 1ull) { if (!done2 && (b >> 8) == (pref2 >> 8)) atomicAdd(&h2[b & 255u], 1u); }
        else                  { if (!done3 && (b >> 8) == (pref3 >> 8)) atomicAdd(&h3[b & 255u], 1u); }
    }
    wpick(h2, pref2, need2, done2, 0, lane);
    wpick(h3, pref3, need3, done3, 0, lane);

    // ---- final sums: strictly-greater + boundary-count * threshold ----
    float s2 = 0.f, s3 = 0.f;
#pragma unroll
    for (int r = 0; r < 64; ++r) {
        u32 b = __float_as_uint(v[r]);
        if ((sm >> r) & 1ull) { if (b > pref2) s2 += v[r]; }
        else                  { if (b > pref3) s3 += v[r]; }
    }
    s2 = wred_sumf(s2);
    s3 = wred_sumf(s3);
    if (lane == 0) {
        float nln = s2 + (float)need2 * __uint_as_float(pref2);
        float nun = s3 + (float)need3 * __uint_as_float(pref3);
        assigned[j] = asg;
        score[j] = nln / nun;
    }
#undef LPW
}

// ---------------- kernel 4: exact top-MU radix select + flab + class hist ----
// u64 key = (score_bits<<32)|(~idx): 8 passes, wave-parallel pick stage.
__global__ __launch_bounds__(1024) void select_kernel(const float* __restrict__ score,
                                                      const int* __restrict__ assigned,
                                                      int* __restrict__ top_tgt,
                                                      int* __restrict__ flab,
                                                      int* __restrict__ histg) {
    __shared__ u64 keys[NN];        // 32 KB
    __shared__ __attribute__((aligned(16))) u32 hist[256];
    __shared__ u64 s_prefix;
    __shared__ u32 s_rem;
    __shared__ int hcls[32];
    __shared__ int s_counter;
    int tid = threadIdx.x;
#pragma unroll
    for (int t = 0; t < 4; ++t) {
        int i = t * 1024 + tid;
        keys[i] = ((u64)__float_as_uint(score[i]) << 32) | (u64)(0xFFFFFFFFu - (u32)i);
    }
    if (tid == 0) { s_prefix = 0ull; s_rem = MUSEL; s_counter = 0; }
    if (tid < 32) hcls[tid] = 0;
    if (tid < 256) hist[tid] = 0u;
    __syncthreads();
    for (int pass = 0; pass < 8; ++pass) {
        int shift = 56 - pass * 8;
        u64 pref = s_prefix;
#pragma unroll
        for (int t = 0; t < 4; ++t) {
            u64 k = keys[t * 1024 + tid];
            bool match = (pass == 0) || ((k >> (shift + 8)) == (pref >> (shift + 8)));
            if (match) atomicAdd(&hist[(u32)(k >> shift) & 255u], 1u);
        }
        __syncthreads();
        if (tid < 64) {               // wave0 parallel pick (zeroes hist)
            int g = 63 - tid;
            uint4 h = *(uint4*)&hist[4 * g];
            *(uint4*)&hist[4 * g] = make_uint4(0u, 0u, 0u, 0u);
            u32 s = h.x + h.y + h.z + h.w, P = s;
#pragma unroll
            for (int o = 1; o < 64; o <<= 1) { u32 tt = __shfl_up(P, o); if (tid >= o) P += tt; }
            u32 need = s_rem;
            unsigned long long bal = __ballot(P >= need);   // nonzero by invariant
            int l0 = __ffsll(bal) - 1;
            u32 c = P - s, b, nn;
            if (c + h.w >= need) { b = 3u; nn = need - c; }
            else { c += h.w; if (c + h.z >= need) { b = 2u; nn = need - c; }
                   else { c += h.z; if (c + h.y >= need) { b = 1u; nn = need - c; }
                          else { c += h.y; b = 0u; nn = need - c; } } }
            if (tid == l0) { s_prefix = pref | ((u64)((u32)(4 * g) + b) << shift); s_rem = nn; }
        }
        __syncthreads();
    }
    u64 thr = s_prefix;   // exact MUSEL-th largest key
#pragma unroll
    for (int t = 0; t < 4; ++t) {
        int i = t * 1024 + tid;
        if (keys[i] >= thr) {
            int p = atomicAdd(&s_counter, 1);
            int idx = (int)(0xFFFFFFFFu - (u32)(keys[i] & 0xFFFFFFFFull));
            top_tgt[p] = idx;
            int a = assigned[idx];
            flab[p] = a;
            atomicAdd(&hcls[a], 1);
        }
    }
    __syncthreads();
    if (tid < 32) histg[tid] = hcls[tid];
}

// ---------------- kernel 6: softmax partial sums (no max shift needed) -------
// sim in (0,1] so exp(v) <= e: direct sums exact-equivalent to max-shifted.
#define JCH 64
__global__ __launch_bounds__(256) void fpart_kernel(const float* __restrict__ simT,
                                                    const int* __restrict__ top_tgt,
                                                    const int* __restrict__ flab,
                                                    const int* __restrict__ labels,
                                                    float* __restrict__ ps,
                                                    float* __restrict__ pt) {
    __shared__ int tt[JCH];
    __shared__ int fl[JCH];
    int tid = threadIdx.x;
    int ci = blockIdx.x, cj = blockIdx.y;
    if (tid < JCH) { tt[tid] = top_tgt[cj * JCH + tid]; fl[tid] = flab[cj * JCH + tid]; }
    __syncthreads();
    int i = ci * 256 + tid;
    int myl = labels[i];
    float s = 0.f, t = 0.f;
#pragma unroll 4
    for (int jj = 0; jj < JCH; ++jj) {
        float v = simT[(size_t)tt[jj] * NN + i];
        float e = __expf(v);
        s += e;
        t += (fl[jj] == myl) ? e : 0.f;
    }
    ps[cj * NN + i] = s;
    pt[cj * NN + i] = t;
}

// ---------------- kernel 7: merge partials -> per-block loss partials --------
__global__ __launch_bounds__(256) void merge_kernel(const float* __restrict__ ps,
                                                    const float* __restrict__ pt,
                                                    const int* __restrict__ labels,
                                                    const int* __restrict__ hist,
                                                    float* __restrict__ partials) {
    int tid = threadIdx.x;
    int i = blockIdx.x * 256 + tid;
    float S = 0.f, T = 0.f;
#pragma unroll
    for (int c = 0; c < 32; ++c) {
        S += ps[c * NN + i];
        T += pt[c * NN + i];
    }
    float contr = T / S;
    int ns = hist[labels[i]];
    bool valid = (ns > 0) && (ns < MUSEL);
    float term = valid ? __logf(contr) : 0.0f;
    float cnt = valid ? 1.0f : 0.0f;
    for (int off = 32; off > 0; off >>= 1) {
        term += __shfl_down(term, off);
        cnt  += __shfl_down(cnt, off);
    }
    __shared__ float rt[4], rc[4];
    int wid = tid >> 6, lane = tid & 63;
    if (lane == 0) { rt[wid] = term; rc[wid] = cnt; }
    __syncthreads();
    if (tid == 0) {
        partials[blockIdx.x * 2]     = rt[0] + rt[1] + rt[2] + rt[3];
        partials[blockIdx.x * 2 + 1] = rc[0] + rc[1] + rc[2] + rc[3];
    }
}

// ---------------- kernel 8: final scalar -------------------------------------
__global__ void final_kernel(const float* __restrict__ partials, float* __restrict__ out) {
    if (threadIdx.x == 0) {
        float s = 0.f, c = 0.f;
        for (int b = 0; b < 16; ++b) { s += partials[b * 2]; c += partials[b * 2 + 1]; }
        out[0] = -s / c;
    }
}

extern "C" void kernel_launch(void* const* d_in, const int* in_sizes, int n_in,
                              void* d_out, int out_size, void* d_ws, size_t ws_size,
                              hipStream_t stream) {
    const float* src    = (const float*)d_in[0];
    const int*   labels = (const int*)d_in[1];
    const float* tgt    = (const float*)d_in[2];
    float* out = (float*)d_out;

    char* ws = (char*)d_ws;
    size_t off = 0;
    float* simT = (float*)(ws + off);             off += (size_t)NN * NN * sizeof(float); // 64 MB
    unsigned short* tgt_hi = (unsigned short*)(ws + off); off += (size_t)NN * DD * 2;     // 2 MB
    unsigned short* tgt_lo = (unsigned short*)(ws + off); off += (size_t)NN * DD * 2;
    unsigned short* src_hi = (unsigned short*)(ws + off); off += (size_t)NN * DD * 2;
    unsigned short* src_lo = (unsigned short*)(ws + off); off += (size_t)NN * DD * 2;
    float* sq_s = (float*)(ws + off);      off += NN * sizeof(float);
    float* sq_t = (float*)(ws + off);      off += NN * sizeof(float);
    float* score = (float*)(ws + off);     off += NN * sizeof(float);
    int*   assigned = (int*)(ws + off);    off += NN * sizeof(int);
    int*   top_tgt = (int*)(ws + off);     off += MUSEL * sizeof(int);
    int*   flab = (int*)(ws + off);        off += MUSEL * sizeof(int);
    int*   hist = (int*)(ws + off);        off += 32 * sizeof(int);
    float* partials = (float*)(ws + off);  off += 32 * sizeof(float);
    // ps/pt (512 KB each) alias the dead-after-GEMM bf16 planes (2 MB each)
    float* ps = (float*)tgt_lo;
    float* pt = (float*)src_hi;

    prep_kernel<<<2 * NN, 256, 0, stream>>>(src, tgt, src_hi, src_lo, tgt_hi, tgt_lo, sq_s, sq_t);
    gemm_mfma_kernel<<<1024, 256, 0, stream>>>(tgt_hi, tgt_lo, src_hi, src_lo, sq_s, sq_t, simT);
    percol_kernel<<<NN / 2, 128, 0, stream>>>(simT, labels, assigned, score);
    select_kernel<<<1, 1024, 0, stream>>>(score, assigned, top_tgt, flab, hist);
    fpart_kernel<<<dim3(16, 32), 256, 0, stream>>>(simT, top_tgt, flab, labels, ps, pt);
    merge_kernel<<<16, 256, 0, stream>>>(ps, pt, labels, hist, partials);
    final_kernel<<<1, 64, 0, stream>>>(partials, out);
}

// Round 9
// 203.296 us; speedup vs baseline: 2.0889x; 1.1518x over previous
//
#include <hip/hip_runtime.h>
#include <hip/hip_bf16.h>
#include <cfloat>

#define NN 4096
#define DD 256
#define KTOP 10
#define MTOP 5
#define MUSEL 2048
#define NCLS 31

typedef unsigned long long u64;
typedef unsigned int u32;
typedef __attribute__((ext_vector_type(8))) short short8;   // 8 bf16 (4 VGPRs)
typedef __attribute__((ext_vector_type(4))) float f32x4;    // MFMA acc

static __device__ __forceinline__ unsigned short f2bf(float x) {
    u32 u = __float_as_uint(x);
    u32 r = (u + 0x7FFFu + ((u >> 16) & 1u)) >> 16;   // RNE, no NaN inputs here
    return (unsigned short)r;
}
static __device__ __forceinline__ float bf2f(unsigned short h) {
    return __uint_as_float((u32)h << 16);
}

// wave min/max reduce (result in all lanes)
static __device__ __forceinline__ void wredmm(u32& mn, u32& mx) {
#pragma unroll
    for (int o = 1; o < 64; o <<= 1) {
        u32 a = __shfl_xor(mn, o); mn = a < mn ? a : mn;
        u32 b = __shfl_xor(mx, o); mx = b > mx ? b : mx;
    }
}

// radix pick: one wave scans 256-bin hist (desc), crossing-point of `need`.
// Zeroes the bins it read (ready for next pass). If total < need: done=1,
// pref=0, need=0 ("take all" semantics downstream).
static __device__ __forceinline__ void radix_pick_z(u32* hist, u32* pref, u32* need,
                                                    u32* done, int shift, int lane) {
    int g = 63 - lane;                       // lane asc == bins desc
    u32 h0 = hist[4 * g + 0], h1 = hist[4 * g + 1];
    u32 h2 = hist[4 * g + 2], h3 = hist[4 * g + 3];
    hist[4 * g + 0] = 0u; hist[4 * g + 1] = 0u;
    hist[4 * g + 2] = 0u; hist[4 * g + 3] = 0u;
    u32 s = h0 + h1 + h2 + h3;
    u32 P = s;
#pragma unroll
    for (int o = 1; o < 64; o <<= 1) { u32 t = __shfl_up(P, o); if (lane >= o) P += t; }
    u32 nd = *need;
    unsigned long long bal = __ballot(P >= nd);
    if (bal == 0ull) {
        if (lane == 0) { *done = 1u; *pref = 0u; *need = 0u; }
        return;
    }
    int l0 = __ffsll(bal) - 1;
    if (lane == l0) {
        u32 c = P - s;
        u32 b;
        if (c + h3 >= nd) b = 3u;
        else { c += h3; if (c + h2 >= nd) b = 2u;
               else { c += h2; if (c + h1 >= nd) b = 1u;
                      else { c += h1; b = 0u; } } }
        *pref |= (u32)(4 * g + (int)b) << shift;
        *need = nd - c;
    }
}

// ---------------- kernel 0: fused fp32->bf16 hi/lo planes + row sq norms -----
__global__ __launch_bounds__(256) void prep_kernel(const float* __restrict__ src,
                                                   const float* __restrict__ tgt,
                                                   unsigned short* __restrict__ src_hi,
                                                   unsigned short* __restrict__ src_lo,
                                                   unsigned short* __restrict__ tgt_hi,
                                                   unsigned short* __restrict__ tgt_lo,
                                                   float* __restrict__ sq_s,
                                                   float* __restrict__ sq_t) {
    int r = blockIdx.x;                      // 0..2N-1
    bool isT = r >= NN;
    int rr = isT ? r - NN : r;
    const float* base = (isT ? tgt : src) + (size_t)rr * DD;
    float x = base[threadIdx.x];
    unsigned short h = f2bf(x);
    unsigned short l = f2bf(x - bf2f(h));
    size_t o = (size_t)rr * DD + threadIdx.x;
    if (isT) { tgt_hi[o] = h; tgt_lo[o] = l; } else { src_hi[o] = h; src_lo[o] = l; }
    float p = x * x;
    for (int off = 32; off > 0; off >>= 1) p += __shfl_down(p, off);
    __shared__ float red[4];
    int wid = threadIdx.x >> 6, lane = threadIdx.x & 63;
    if (lane == 0) red[wid] = p;
    __syncthreads();
    if (threadIdx.x == 0) {
        float s = red[0] + red[1] + red[2] + red[3];
        if (isT) sq_t[rr] = s; else sq_s[rr] = s;
    }
}

// ---------------- kernel 2: bf16 MFMA GEMM, 4-plane staging ------------------
// dot = hiT.hiS + hiT.loS + loT.hiS. The 3 segments share operand planes, so
// stage all 4 unique planes once per 32-wide K-slice and run 48 MFMAs per
// barrier pair (8 slices) instead of 16 per pair (24 steps): staging insts
// 96->64/wave, barriers 48->16. 32KB LDS keeps 4-5 blocks/CU for overlap.
static __device__ __forceinline__ void gload(const unsigned short* g, short* l) {
    __builtin_amdgcn_global_load_lds((const __attribute__((address_space(1))) void*)g,
                                     (__attribute__((address_space(3))) void*)l, 16, 0, 0);
}

__global__ __launch_bounds__(256) void gemm_mfma_kernel(
        const unsigned short* __restrict__ tgt_hi, const unsigned short* __restrict__ tgt_lo,
        const unsigned short* __restrict__ src_hi, const unsigned short* __restrict__ src_lo,
        const float* __restrict__ sq_s, const float* __restrict__ sq_t,
        float* __restrict__ simT) {
    __shared__ short Ahi[128 * 32];   // tgt_hi tile [row j'][k], 64B rows
    __shared__ short Alo[128 * 32];
    __shared__ short Bhi[128 * 32];   // src_hi tile [row i'][k]
    __shared__ short Blo[128 * 32];
    int tid = threadIdx.x;
    int wid = tid >> 6, lane = tid & 63;
    // bijective XCD swizzle (1024 blocks % 8 == 0)
    int lin = blockIdx.x;
    int wg = (lin & 7) * 128 + (lin >> 3);
    int i0 = (wg & 31) * 128;
    int j0 = (wg >> 5) * 128;
    int wr = wid >> 1, wc = wid & 1;

    f32x4 acc[4][4];
#pragma unroll
    for (int m = 0; m < 4; ++m)
#pragma unroll
        for (int n = 0; n < 4; ++n) acc[m][n] = (f32x4){0.f, 0.f, 0.f, 0.f};

    int srow = wid * 32 + (lane >> 2);    // wave covers tile rows [wid*32, wid*32+32)
    int skoff = (lane & 3) * 8;
    int fr = lane & 15;
    int kq = (lane >> 4) * 8;

    for (int t = 0; t < 8; ++t) {
        int kk = t * 32;
#pragma unroll
        for (int r = 0; r < 2; ++r) {
            int row = srow + r * 16;
            size_t goA = (size_t)(j0 + row) * DD + kk + skoff;
            size_t goB = (size_t)(i0 + row) * DD + kk + skoff;
            int ldo = (wid * 2 + r) * 512;     // wave-uniform LDS chunk base
            gload(tgt_hi + goA, Ahi + ldo);
            gload(tgt_lo + goA, Alo + ldo);
            gload(src_hi + goB, Bhi + ldo);
            gload(src_lo + goB, Blo + ldo);
        }
        __syncthreads();                       // drains vmcnt: planes ready
        short8 ah[4], bh[4], bl[4], al[4];
#pragma unroll
        for (int m = 0; m < 4; ++m) {
            int ra = (wr * 64 + m * 16 + fr) * 32 + kq;
            int rb = (wc * 64 + m * 16 + fr) * 32 + kq;
            ah[m] = *(const short8*)(Ahi + ra);
            bh[m] = *(const short8*)(Bhi + rb);
        }
#pragma unroll
        for (int m = 0; m < 4; ++m)
#pragma unroll
            for (int n = 0; n < 4; ++n)
                acc[m][n] = __builtin_amdgcn_mfma_f32_16x16x32_bf16(ah[m], bh[n], acc[m][n], 0, 0, 0);
#pragma unroll
        for (int m = 0; m < 4; ++m)
            bl[m] = *(const short8*)(Blo + (wc * 64 + m * 16 + fr) * 32 + kq);
#pragma unroll
        for (int m = 0; m < 4; ++m)
#pragma unroll
            for (int n = 0; n < 4; ++n)
                acc[m][n] = __builtin_amdgcn_mfma_f32_16x16x32_bf16(ah[m], bl[n], acc[m][n], 0, 0, 0);
#pragma unroll
        for (int m = 0; m < 4; ++m)
            al[m] = *(const short8*)(Alo + (wr * 64 + m * 16 + fr) * 32 + kq);
#pragma unroll
        for (int m = 0; m < 4; ++m)
#pragma unroll
            for (int n = 0; n < 4; ++n)
                acc[m][n] = __builtin_amdgcn_mfma_f32_16x16x32_bf16(al[m], bh[n], acc[m][n], 0, 0, 0);
        __syncthreads();                       // protect LDS reuse
    }

    int fq = lane >> 4;
#pragma unroll
    for (int m = 0; m < 4; ++m) {
#pragma unroll
        for (int n = 0; n < 4; ++n) {
            int i = i0 + wc * 64 + n * 16 + fr;
            float ss = sq_s[i];
#pragma unroll
            for (int r = 0; r < 4; ++r) {
                int j = j0 + wr * 64 + m * 16 + fq * 4 + r;
                float d2 = fmaxf(ss + sq_t[j] - 2.0f * acc[m][n][r], 0.0f);
                simT[(size_t)j * NN + i] = 1.0f / (sqrtf(d2) + 1.0f);
            }
        }
    }
}

// ---------------- kernel 3: per-column radix top-k, 2 columns per block ------
// (r6 version, known-good 67us: 4 waves, 16+16 vals/thread, low VGPR ->
// occupancy is the latency-hiding mechanism; r8's 1-wave/col regressed.)
// Streams: 0=ph1-A, 1=ph1-B, 2=A-same, 3=A-diff, 4=B-same, 5=B-diff.
__global__ __launch_bounds__(256) void percol_kernel(const float* __restrict__ simT,
                                                     const int* __restrict__ labels,
                                                     int* __restrict__ assigned,
                                                     float* __restrict__ score) {
    __shared__ u32 histA2[256], histA3[256], histB2[256], histB3[256];
    __shared__ u32 votebinA[NCLS], votebinB[NCLS];
    __shared__ u32 eqlistA[64], eqlistB[64];
    __shared__ u32 s_eqcntA, s_eqcntB;
    __shared__ u32 s_pref[6], s_need[6], s_done[6];
    __shared__ u32 s_p0mask;
    __shared__ int s_asgA, s_asgB;
    __shared__ u32 s_mm[4][8];
    __shared__ float s_red[4][4];
    int tid = threadIdx.x, lane = tid & 63, wid = tid >> 6;
    int jA = blockIdx.x * 2, jB = jA + 1;

    float vA[16], vB[16];
    u32 labp[4];
    {
        const float4* pA = (const float4*)(simT + (size_t)jA * NN + tid * 16);
        const float4* pB = (const float4*)(simT + (size_t)jB * NN + tid * 16);
        const int4*  pL = (const int4*)(labels + tid * 16);
#pragma unroll
        for (int q = 0; q < 4; ++q) {
            float4 a = pA[q], b = pB[q];
            vA[q * 4 + 0] = a.x; vA[q * 4 + 1] = a.y; vA[q * 4 + 2] = a.z; vA[q * 4 + 3] = a.w;
            vB[q * 4 + 0] = b.x; vB[q * 4 + 1] = b.y; vB[q * 4 + 2] = b.z; vB[q * 4 + 3] = b.w;
            int4 l = pL[q];
            labp[q] = (u32)l.x | ((u32)l.y << 8) | ((u32)l.z << 16) | ((u32)l.w << 24);
        }
    }
#define LAB(r) ((int)((labp[(r) >> 2] >> (((r) & 3) * 8)) & 0xFFu))
    histA2[tid] = 0u; histA3[tid] = 0u; histB2[tid] = 0u; histB3[tid] = 0u;
    if (tid < NCLS) { votebinA[tid] = 0u; votebinB[tid] = 0u; }
    if (tid == 0) { s_eqcntA = 0u; s_eqcntB = 0u; }

    // ---- phase 1: threshold of top-10 (per column) ----
    {
        u32 mnA = ~0u, mxA = 0u, mnB = ~0u, mxB = 0u;
#pragma unroll
        for (int r = 0; r < 16; ++r) {
            u32 a = __float_as_uint(vA[r]); mnA = a < mnA ? a : mnA; mxA = a > mxA ? a : mxA;
            u32 b = __float_as_uint(vB[r]); mnB = b < mnB ? b : mnB; mxB = b > mxB ? b : mxB;
        }
        wredmm(mnA, mxA); wredmm(mnB, mxB);
        if (lane == 0) { s_mm[wid][0] = mnA; s_mm[wid][1] = mxA; s_mm[wid][2] = mnB; s_mm[wid][3] = mxB; }
    }
    __syncthreads();
    if (tid == 0) {
        u32 mn = ~0u, mx = 0u, mn2 = ~0u, mx2 = 0u;
        for (int w = 0; w < 4; ++w) {
            mn = min(mn, s_mm[w][0]); mx = max(mx, s_mm[w][1]);
            mn2 = min(mn2, s_mm[w][2]); mx2 = max(mx2, s_mm[w][3]);
        }
        u32 m0 = 0u;
        s_need[0] = KTOP; s_done[0] = 0u;
        s_need[1] = KTOP; s_done[1] = 0u;
        if ((mn >> 24) == (mx >> 24)) s_pref[0] = mx & 0xFF000000u; else { s_pref[0] = 0u; m0 |= 1u; }
        if ((mn2 >> 24) == (mx2 >> 24)) s_pref[1] = mx2 & 0xFF000000u; else { s_pref[1] = 0u; m0 |= 2u; }
        s_p0mask = m0;
    }
    __syncthreads();
    if (s_p0mask) {      // rare fallback: byte-0 histogram
        u32 m0 = s_p0mask;
#pragma unroll
        for (int r = 0; r < 16; ++r) {
            if (m0 & 1u) atomicAdd(&histA2[__float_as_uint(vA[r]) >> 24], 1u);
            if (m0 & 2u) atomicAdd(&histB2[__float_as_uint(vB[r]) >> 24], 1u);
        }
        __syncthreads();
        if (wid == 0 && (m0 & 1u)) radix_pick_z(histA2, &s_pref[0], &s_need[0], &s_done[0], 24, lane);
        if (wid == 1 && (m0 & 2u)) radix_pick_z(histB2, &s_pref[1], &s_need[1], &s_done[1], 24, lane);
        __syncthreads();
    }
    for (int pass = 1; pass < 4; ++pass) {
        int shift = 24 - pass * 8;
        u32 pA = s_pref[0], pB = s_pref[1];
#pragma unroll
        for (int r = 0; r < 16; ++r) {
            u32 a = __float_as_uint(vA[r]);
            if ((a >> (shift + 8)) == (pA >> (shift + 8))) atomicAdd(&histA2[(a >> shift) & 255u], 1u);
            u32 b = __float_as_uint(vB[r]);
            if ((b >> (shift + 8)) == (pB >> (shift + 8))) atomicAdd(&histB2[(b >> shift) & 255u], 1u);
        }
        __syncthreads();
        if (wid == 0) radix_pick_z(histA2, &s_pref[0], &s_need[0], &s_done[0], shift, lane);
        if (wid == 1) radix_pick_z(histB2, &s_pref[1], &s_need[1], &s_done[1], shift, lane);
        __syncthreads();
    }
    u32 v10A = s_pref[0], neqA = s_need[0];
    u32 v10B = s_pref[1], neqB = s_need[1];

    // ---- votes + argmax (first-max tie-break == jnp.argmax) ----
#pragma unroll
    for (int r = 0; r < 16; ++r) {
        int idx = tid * 16 + r;
        u32 a = __float_as_uint(vA[r]);
        if (a > v10A) atomicAdd(&votebinA[LAB(r)], 1u);
        else if (a == v10A) {
            u32 p = atomicAdd(&s_eqcntA, 1u);
            if (p < 64u) eqlistA[p] = ((u32)idx << 8) | (u32)LAB(r);
        }
        u32 b = __float_as_uint(vB[r]);
        if (b > v10B) atomicAdd(&votebinB[LAB(r)], 1u);
        else if (b == v10B) {
            u32 p = atomicAdd(&s_eqcntB, 1u);
            if (p < 64u) eqlistB[p] = ((u32)idx << 8) | (u32)LAB(r);
        }
    }
    __syncthreads();
    if (tid == 0) {          // boundary ties: neqA smallest-idx at v == v10
        int ne = (int)min(s_eqcntA, 64u);
        for (u32 k = 0; k < neqA; ++k) {
            u32 best = ~0u; int bi = -1;
            for (int e = 0; e < ne; ++e) if (eqlistA[e] < best) { best = eqlistA[e]; bi = e; }
            if (bi >= 0) { votebinA[best & 0xFFu] += 1u; eqlistA[bi] = ~0u; }
        }
    } else if (tid == 64) {
        int ne = (int)min(s_eqcntB, 64u);
        for (u32 k = 0; k < neqB; ++k) {
            u32 best = ~0u; int bi = -1;
            for (int e = 0; e < ne; ++e) if (eqlistB[e] < best) { best = eqlistB[e]; bi = e; }
            if (bi >= 0) { votebinB[best & 0xFFu] += 1u; eqlistB[bi] = ~0u; }
        }
    }
    __syncthreads();
    if (wid == 0) {
        u32 vk = (lane < NCLS) ? ((votebinA[lane] << 6) | (u32)(63 - lane)) : 0u;
#pragma unroll
        for (int o = 1; o < 64; o <<= 1) { u32 t = __shfl_xor(vk, o); vk = vk > t ? vk : t; }
        if (lane == 0) s_asgA = 63 - (int)(vk & 63u);
    } else if (wid == 1) {
        u32 vk = (lane < NCLS) ? ((votebinB[lane] << 6) | (u32)(63 - lane)) : 0u;
#pragma unroll
        for (int o = 1; o < 64; o <<= 1) { u32 t = __shfl_xor(vk, o); vk = vk > t ? vk : t; }
        if (lane == 0) s_asgB = 63 - (int)(vk & 63u);
    }
    __syncthreads();
    int asgA = s_asgA, asgB = s_asgB;

    // ---- phases 2/3: same/diff-label top-5 thresholds, 4 streams ----
    u32 mA = 0u, mB = 0u;
#pragma unroll
    for (int r = 0; r < 16; ++r) {
        if (LAB(r) == asgA) mA |= 1u << r;
        if (LAB(r) == asgB) mB |= 1u << r;
    }
    {
        u32 mn2 = ~0u, mx2 = 0u, mn3 = ~0u, mx3 = 0u;
        u32 mn4 = ~0u, mx4 = 0u, mn5 = ~0u, mx5 = 0u;
#pragma unroll
        for (int r = 0; r < 16; ++r) {
            u32 a = __float_as_uint(vA[r]);
            if ((mA >> r) & 1u) { mn2 = a < mn2 ? a : mn2; mx2 = a > mx2 ? a : mx2; }
            else                { mn3 = a < mn3 ? a : mn3; mx3 = a > mx3 ? a : mx3; }
            u32 b = __float_as_uint(vB[r]);
            if ((mB >> r) & 1u) { mn4 = b < mn4 ? b : mn4; mx4 = b > mx4 ? b : mx4; }
            else                { mn5 = b < mn5 ? b : mn5; mx5 = b > mx5 ? b : mx5; }
        }
        wredmm(mn2, mx2); wredmm(mn3, mx3); wredmm(mn4, mx4); wredmm(mn5, mx5);
        if (lane == 0) {
            s_mm[wid][0] = mn2; s_mm[wid][1] = mx2; s_mm[wid][2] = mn3; s_mm[wid][3] = mx3;
            s_mm[wid][4] = mn4; s_mm[wid][5] = mx4; s_mm[wid][6] = mn5; s_mm[wid][7] = mx5;
        }
    }
    __syncthreads();
    if (tid == 0) {
        u32 m0 = 0u;
        for (int s = 0; s < 4; ++s) {
            u32 mn = ~0u, mx = 0u;
            for (int w = 0; w < 4; ++w) { mn = min(mn, s_mm[w][s * 2]); mx = max(mx, s_mm[w][s * 2 + 1]); }
            int st = 2 + s;
            s_need[st] = MTOP; s_done[st] = 0u;
            if (mx == 0u) { s_pref[st] = 0u; s_done[st] = 1u; s_need[st] = 0u; }  // empty stream
            else if ((mn >> 24) == (mx >> 24)) s_pref[st] = mx & 0xFF000000u;
            else { s_pref[st] = 0u; m0 |= 1u << st; }
        }
        s_p0mask = m0;
    }
    __syncthreads();
    if (s_p0mask) {      // rare fallback
        u32 m0 = s_p0mask;
#pragma unroll
        for (int r = 0; r < 16; ++r) {
            u32 a = __float_as_uint(vA[r]);
            if ((mA >> r) & 1u) { if (m0 & 4u)  atomicAdd(&histA2[a >> 24], 1u); }
            else                { if (m0 & 8u)  atomicAdd(&histA3[a >> 24], 1u); }
            u32 b = __float_as_uint(vB[r]);
            if ((mB >> r) & 1u) { if (m0 & 16u) atomicAdd(&histB2[b >> 24], 1u); }
            else                { if (m0 & 32u) atomicAdd(&histB3[b >> 24], 1u); }
        }
        __syncthreads();
        if (wid == 0 && (m0 & 4u))  radix_pick_z(histA2, &s_pref[2], &s_need[2], &s_done[2], 24, lane);
        if (wid == 1 && (m0 & 8u))  radix_pick_z(histA3, &s_pref[3], &s_need[3], &s_done[3], 24, lane);
        if (wid == 2 && (m0 & 16u)) radix_pick_z(histB2, &s_pref[4], &s_need[4], &s_done[4], 24, lane);
        if (wid == 3 && (m0 & 32u)) radix_pick_z(histB3, &s_pref[5], &s_need[5], &s_done[5], 24, lane);
        __syncthreads();
    }
    for (int pass = 1; pass < 4; ++pass) {
        int shift = 24 - pass * 8;
        u32 p2 = s_pref[2], p3 = s_pref[3], p4 = s_pref[4], p5 = s_pref[5];
        u32 d2 = s_done[2], d3 = s_done[3], d4 = s_done[4], d5 = s_done[5];
#pragma unroll
        for (int r = 0; r < 16; ++r) {
            u32 a = __float_as_uint(vA[r]);
            if ((mA >> r) & 1u) { if (!d2 && (a >> (shift + 8)) == (p2 >> (shift + 8))) atomicAdd(&histA2[(a >> shift) & 255u], 1u); }
            else                { if (!d3 && (a >> (shift + 8)) == (p3 >> (shift + 8))) atomicAdd(&histA3[(a >> shift) & 255u], 1u); }
            u32 b = __float_as_uint(vB[r]);
            if ((mB >> r) & 1u) { if (!d4 && (b >> (shift + 8)) == (p4 >> (shift + 8))) atomicAdd(&histB2[(b >> shift) & 255u], 1u); }
            else                { if (!d5 && (b >> (shift + 8)) == (p5 >> (shift + 8))) atomicAdd(&histB3[(b >> shift) & 255u], 1u); }
        }
        __syncthreads();
        if (wid == 0 && !s_done[2]) radix_pick_z(histA2, &s_pref[2], &s_need[2], &s_done[2], shift, lane);
        if (wid == 1 && !s_done[3]) radix_pick_z(histA3, &s_pref[3], &s_need[3], &s_done[3], shift, lane);
        if (wid == 2 && !s_done[4]) radix_pick_z(histB2, &s_pref[4], &s_need[4], &s_done[4], shift, lane);
        if (wid == 3 && !s_done[5]) radix_pick_z(histB3, &s_pref[5], &s_need[5], &s_done[5], shift, lane);
        __syncthreads();
    }

    // ---- final sums: strictly-greater + boundary-count * threshold ----
    u32 tA2 = s_pref[2], tA3 = s_pref[3], tB2 = s_pref[4], tB3 = s_pref[5];
    float pA2 = 0.f, pA3 = 0.f, pB2 = 0.f, pB3 = 0.f;
#pragma unroll
    for (int r = 0; r < 16; ++r) {
        u32 a = __float_as_uint(vA[r]);
        if ((mA >> r) & 1u) { if (a > tA2) pA2 += vA[r]; }
        else                { if (a > tA3) pA3 += vA[r]; }
        u32 b = __float_as_uint(vB[r]);
        if ((mB >> r) & 1u) { if (b > tB2) pB2 += vB[r]; }
        else                { if (b > tB3) pB3 += vB[r]; }
    }
#pragma unroll
    for (int o = 1; o < 64; o <<= 1) {
        pA2 += __shfl_xor(pA2, o);
        pA3 += __shfl_xor(pA3, o);
        pB2 += __shfl_xor(pB2, o);
        pB3 += __shfl_xor(pB3, o);
    }
    if (lane == 0) { s_red[wid][0] = pA2; s_red[wid][1] = pA3; s_red[wid][2] = pB2; s_red[wid][3] = pB3; }
    __syncthreads();
    if (tid == 0) {
        float nln = s_red[0][0] + s_red[1][0] + s_red[2][0] + s_red[3][0]
                  + (float)s_need[2] * __uint_as_float(s_pref[2]);
        float nun = s_red[0][1] + s_red[1][1] + s_red[2][1] + s_red[3][1]
                  + (float)s_need[3] * __uint_as_float(s_pref[3]);
        assigned[jA] = asgA;
        score[jA] = nln / nun;
    } else if (tid == 64) {
        float nln = s_red[0][2] + s_red[1][2] + s_red[2][2] + s_red[3][2]
                  + (float)s_need[4] * __uint_as_float(s_pref[4]);
        float nun = s_red[0][3] + s_red[1][3] + s_red[2][3] + s_red[3][3]
                  + (float)s_need[5] * __uint_as_float(s_pref[5]);
        assigned[jB] = asgB;
        score[jB] = nln / nun;
    }
#undef LAB
}

// ---------------- kernel 4: exact top-MU radix select + flab + class hist ----
// u64 key = (score_bits<<32)|(~idx): 8 passes, wave-parallel pick stage.
__global__ __launch_bounds__(1024) void select_kernel(const float* __restrict__ score,
                                                      const int* __restrict__ assigned,
                                                      int* __restrict__ top_tgt,
                                                      int* __restrict__ flab,
                                                      int* __restrict__ histg) {
    __shared__ u64 keys[NN];        // 32 KB
    __shared__ __attribute__((aligned(16))) u32 hist[256];
    __shared__ u64 s_prefix;
    __shared__ u32 s_rem;
    __shared__ int hcls[32];
    __shared__ int s_counter;
    int tid = threadIdx.x;
#pragma unroll
    for (int t = 0; t < 4; ++t) {
        int i = t * 1024 + tid;
        keys[i] = ((u64)__float_as_uint(score[i]) << 32) | (u64)(0xFFFFFFFFu - (u32)i);
    }
    if (tid == 0) { s_prefix = 0ull; s_rem = MUSEL; s_counter = 0; }
    if (tid < 32) hcls[tid] = 0;
    if (tid < 256) hist[tid] = 0u;
    __syncthreads();
    for (int pass = 0; pass < 8; ++pass) {
        int shift = 56 - pass * 8;
        u64 pref = s_prefix;
#pragma unroll
        for (int t = 0; t < 4; ++t) {
            u64 k = keys[t * 1024 + tid];
            bool match = (pass == 0) || ((k >> (shift + 8)) == (pref >> (shift + 8)));
            if (match) atomicAdd(&hist[(u32)(k >> shift) & 255u], 1u);
        }
        __syncthreads();
        if (tid < 64) {               // wave0 parallel pick (zeroes hist)
            int g = 63 - tid;
            uint4 h = *(uint4*)&hist[4 * g];
            *(uint4*)&hist[4 * g] = make_uint4(0u, 0u, 0u, 0u);
            u32 s = h.x + h.y + h.z + h.w, P = s;
#pragma unroll
            for (int o = 1; o < 64; o <<= 1) { u32 tt = __shfl_up(P, o); if (tid >= o) P += tt; }
            u32 need = s_rem;
            unsigned long long bal = __ballot(P >= need);   // nonzero by invariant
            int l0 = __ffsll(bal) - 1;
            u32 c = P - s, b, nn;
            if (c + h.w >= need) { b = 3u; nn = need - c; }
            else { c += h.w; if (c + h.z >= need) { b = 2u; nn = need - c; }
                   else { c += h.z; if (c + h.y >= need) { b = 1u; nn = need - c; }
                          else { c += h.y; b = 0u; nn = need - c; } } }
            if (tid == l0) { s_prefix = pref | ((u64)((u32)(4 * g) + b) << shift); s_rem = nn; }
        }
        __syncthreads();
    }
    u64 thr = s_prefix;   // exact MUSEL-th largest key
#pragma unroll
    for (int t = 0; t < 4; ++t) {
        int i = t * 1024 + tid;
        if (keys[i] >= thr) {
            int p = atomicAdd(&s_counter, 1);
            int idx = (int)(0xFFFFFFFFu - (u32)(keys[i] & 0xFFFFFFFFull));
            top_tgt[p] = idx;
            int a = assigned[idx];
            flab[p] = a;
            atomicAdd(&hcls[a], 1);
        }
    }
    __syncthreads();
    if (tid < 32) histg[tid] = hcls[tid];
}

// ---------------- kernel 6: softmax partial sums (no max shift needed) -------
// sim in (0,1] so exp(v) <= e: direct sums exact-equivalent to max-shifted.
#define JCH 64
__global__ __launch_bounds__(256) void fpart_kernel(const float* __restrict__ simT,
                                                    const int* __restrict__ top_tgt,
                                                    const int* __restrict__ flab,
                                                    const int* __restrict__ labels,
                                                    float* __restrict__ ps,
                                                    float* __restrict__ pt) {
    __shared__ int tt[JCH];
    __shared__ int fl[JCH];
    int tid = threadIdx.x;
    int ci = blockIdx.x, cj = blockIdx.y;
    if (tid < JCH) { tt[tid] = top_tgt[cj * JCH + tid]; fl[tid] = flab[cj * JCH + tid]; }
    __syncthreads();
    int i = ci * 256 + tid;
    int myl = labels[i];
    float s = 0.f, t = 0.f;
#pragma unroll 4
    for (int jj = 0; jj < JCH; ++jj) {
        float v = simT[(size_t)tt[jj] * NN + i];
        float e = __expf(v);
        s += e;
        t += (fl[jj] == myl) ? e : 0.f;
    }
    ps[cj * NN + i] = s;
    pt[cj * NN + i] = t;
}

// ---------------- kernel 7: merge partials -> per-block loss partials --------
__global__ __launch_bounds__(256) void merge_kernel(const float* __restrict__ ps,
                                                    const float* __restrict__ pt,
                                                    const int* __restrict__ labels,
                                                    const int* __restrict__ hist,
                                                    float* __restrict__ partials) {
    int tid = threadIdx.x;
    int i = blockIdx.x * 256 + tid;
    float S = 0.f, T = 0.f;
#pragma unroll
    for (int c = 0; c < 32; ++c) {
        S += ps[c * NN + i];
        T += pt[c * NN + i];
    }
    float contr = T / S;
    int ns = hist[labels[i]];
    bool valid = (ns > 0) && (ns < MUSEL);
    float term = valid ? __logf(contr) : 0.0f;
    float cnt = valid ? 1.0f : 0.0f;
    for (int off = 32; off > 0; off >>= 1) {
        term += __shfl_down(term, off);
        cnt  += __shfl_down(cnt, off);
    }
    __shared__ float rt[4], rc[4];
    int wid = tid >> 6, lane = tid & 63;
    if (lane == 0) { rt[wid] = term; rc[wid] = cnt; }
    __syncthreads();
    if (tid == 0) {
        partials[blockIdx.x * 2]     = rt[0] + rt[1] + rt[2] + rt[3];
        partials[blockIdx.x * 2 + 1] = rc[0] + rc[1] + rc[2] + rc[3];
    }
}

// ---------------- kernel 8: final scalar -------------------------------------
__global__ void final_kernel(const float* __restrict__ partials, float* __restrict__ out) {
    if (threadIdx.x == 0) {
        float s = 0.f, c = 0.f;
        for (int b = 0; b < 16; ++b) { s += partials[b * 2]; c += partials[b * 2 + 1]; }
        out[0] = -s / c;
    }
}

extern "C" void kernel_launch(void* const* d_in, const int* in_sizes, int n_in,
                              void* d_out, int out_size, void* d_ws, size_t ws_size,
                              hipStream_t stream) {
    const float* src    = (const float*)d_in[0];
    const int*   labels = (const int*)d_in[1];
    const float* tgt    = (const float*)d_in[2];
    float* out = (float*)d_out;

    char* ws = (char*)d_ws;
    size_t off = 0;
    float* simT = (float*)(ws + off);             off += (size_t)NN * NN * sizeof(float); // 64 MB
    unsigned short* tgt_hi = (unsigned short*)(ws + off); off += (size_t)NN * DD * 2;     // 2 MB
    unsigned short* tgt_lo = (unsigned short*)(ws + off); off += (size_t)NN * DD * 2;
    unsigned short* src_hi = (unsigned short*)(ws + off); off += (size_t)NN * DD * 2;
    unsigned short* src_lo = (unsigned short*)(ws + off); off += (size_t)NN * DD * 2;
    float* sq_s = (float*)(ws + off);      off += NN * sizeof(float);
    float* sq_t = (float*)(ws + off);      off += NN * sizeof(float);
    float* score = (float*)(ws + off);     off += NN * sizeof(float);
    int*   assigned = (int*)(ws + off);    off += NN * sizeof(int);
    int*   top_tgt = (int*)(ws + off);     off += MUSEL * sizeof(int);
    int*   flab = (int*)(ws + off);        off += MUSEL * sizeof(int);
    int*   hist = (int*)(ws + off);        off += 32 * sizeof(int);
    float* partials = (float*)(ws + off);  off += 32 * sizeof(float);
    // ps/pt (512 KB each) alias the dead-after-GEMM bf16 planes (2 MB each)
    float* ps = (float*)tgt_lo;
    float* pt = (float*)src_hi;

    prep_kernel<<<2 * NN, 256, 0, stream>>>(src, tgt, src_hi, src_lo, tgt_hi, tgt_lo, sq_s, sq_t);
    gemm_mfma_kernel<<<1024, 256, 0, stream>>>(tgt_hi, tgt_lo, src_hi, src_lo, sq_s, sq_t, simT);
    percol_kernel<<<NN / 2, 256, 0, stream>>>(simT, labels, assigned, score);
    select_kernel<<<1, 1024, 0, stream>>>(score, assigned, top_tgt, flab, hist);
    fpart_kernel<<<dim3(16, 32), 256, 0, stream>>>(simT, top_tgt, flab, labels, ps, pt);
    merge_kernel<<<16, 256, 0, stream>>>(ps, pt, labels, hist, partials);
    final_kernel<<<1, 64, 0, stream>>>(partials, out);
}